// Round 14
// baseline (490.498 us; speedup 1.0000x reference)
//
#include <hip/hip_runtime.h>

#define N_NODES 50000
#define N_EDGES 800000
#define N_GRAPHS 2048
#define ND 64
#define NL 3
#define WF_STRIDE 14336   // old path u32 per layer
#define WF2_STRIDE 12288  // fast path u32 per layer: w0ab hi 4096 | lo 4096 | w1 hi 2048 | lo 2048
#define GRU_STRIDE 24576  // gru frags u32 per layer
#define PN (65 * 192)     // P temp per layer: rows 0..63 = W1@Wih, row 64 = b1@Wih
#define LUTN (81 * 64)    // per-layer edge-attr LUT

#define ATOMIC_ADD_F32(p, v) unsafeAtomicAdd((p), (v))

typedef __attribute__((ext_vector_type(8))) short short8;
typedef __attribute__((ext_vector_type(4))) float f32x4;

union Frag { unsigned int u[4]; short8 s; };

__device__ __forceinline__ short8 mk4(unsigned int a, unsigned int b,
                                      unsigned int c, unsigned int d) {
    Frag f; f.u[0] = a; f.u[1] = b; f.u[2] = c; f.u[3] = d; return f.s;
}

__device__ __forceinline__ float bf2f(unsigned short u) {
    return __uint_as_float(((unsigned int)u) << 16);
}
__device__ __forceinline__ unsigned short f2bf(float f) {
    unsigned int u = __float_as_uint(f);
    unsigned int r = (u + 0x7FFFu + ((u >> 16) & 1u)) >> 16;
    return (unsigned short)r;
}
__device__ __forceinline__ float sigm(float x) { return 1.0f / (1.0f + __expf(-x)); }
__device__ __forceinline__ float tanh_fast(float x) {
    float ax = fabsf(x);
    float e = __expf(-2.0f * ax);
    float t = (1.0f - e) / (1.0f + e);
    return copysignf(t, x);
}

__device__ __forceinline__ void split8(const float* v, unsigned int* hi, unsigned int* lo) {
#pragma unroll
    for (int i = 0; i < 4; i++) {
        float a = v[2 * i], b = v[2 * i + 1];
        unsigned short ah = f2bf(a), bh = f2bf(b);
        unsigned short al = f2bf(a - bf2f(ah));
        unsigned short bl = f2bf(b - bf2f(bh));
        hi[i] = (unsigned int)ah | ((unsigned int)bh << 16);
        lo[i] = (unsigned int)al | ((unsigned int)bl << 16);
    }
}

// ---------------- shared kernels ----------------

__global__ __launch_bounds__(256) void node_enc_kernel(
    const int* __restrict__ x, const float* __restrict__ W,
    const float* __restrict__ b, float* __restrict__ h) {
    int idx = blockIdx.x * 256 + threadIdx.x;
    if (idx >= N_NODES * ND) return;
    int n = idx >> 6, f = idx & 63;
    float acc = b[f];
#pragma unroll
    for (int k = 0; k < 9; k++)
        acc = fmaf((float)x[n * 9 + k], W[k * ND + f], acc);
    h[idx] = acc;
}

// fallback GRU (LDS-staged VALU version)
__global__ __launch_bounds__(256) void gru_kernel(
    float* __restrict__ h, const float* __restrict__ agg,
    const float* __restrict__ Wih, const float* __restrict__ bih,
    const float* __restrict__ Whh, const float* __restrict__ bhh) {
    __shared__ float wsh[64 * 192];
    __shared__ float ab[16][64], hb[16][64];

    int tid = threadIdx.x, w = tid >> 6, lane = tid & 63;
    int base = blockIdx.x * 16;

#pragma unroll
    for (int q = 0; q < 4; q++) {
        int n = base + w * 4 + q;
        int n0 = n < N_NODES ? n : 0;
        ab[w * 4 + q][lane] = agg[n0 * ND + lane];
        hb[w * 4 + q][lane] = h[n0 * ND + lane];
    }
    for (int idx = tid; idx < 64 * 192; idx += 256) {
        int k = idx / 192, j = idx - k * 192;
        wsh[((k >> 2) * 192 + j) * 4 + (k & 3)] = Wih[idx];
    }
    __syncthreads();

    float gi[4][3];
#pragma unroll
    for (int q = 0; q < 4; q++) {
        gi[q][0] = bih[lane]; gi[q][1] = bih[64 + lane]; gi[q][2] = bih[128 + lane];
    }
#pragma unroll 4
    for (int k4 = 0; k4 < 16; k4++) {
        float4 w0v = *reinterpret_cast<const float4*>(&wsh[(k4 * 192 + lane) * 4]);
        float4 w1v = *reinterpret_cast<const float4*>(&wsh[(k4 * 192 + 64 + lane) * 4]);
        float4 w2v = *reinterpret_cast<const float4*>(&wsh[(k4 * 192 + 128 + lane) * 4]);
#pragma unroll
        for (int q = 0; q < 4; q++) {
            float4 a4 = *reinterpret_cast<const float4*>(&ab[w * 4 + q][k4 * 4]);
            gi[q][0] = fmaf(a4.x, w0v.x, gi[q][0]); gi[q][0] = fmaf(a4.y, w0v.y, gi[q][0]);
            gi[q][0] = fmaf(a4.z, w0v.z, gi[q][0]); gi[q][0] = fmaf(a4.w, w0v.w, gi[q][0]);
            gi[q][1] = fmaf(a4.x, w1v.x, gi[q][1]); gi[q][1] = fmaf(a4.y, w1v.y, gi[q][1]);
            gi[q][1] = fmaf(a4.z, w1v.z, gi[q][1]); gi[q][1] = fmaf(a4.w, w1v.w, gi[q][1]);
            gi[q][2] = fmaf(a4.x, w2v.x, gi[q][2]); gi[q][2] = fmaf(a4.y, w2v.y, gi[q][2]);
            gi[q][2] = fmaf(a4.z, w2v.z, gi[q][2]); gi[q][2] = fmaf(a4.w, w2v.w, gi[q][2]);
        }
    }
    __syncthreads();
    for (int idx = tid; idx < 64 * 192; idx += 256) {
        int k = idx / 192, j = idx - k * 192;
        wsh[((k >> 2) * 192 + j) * 4 + (k & 3)] = Whh[idx];
    }
    __syncthreads();

    float gh[4][3];
#pragma unroll
    for (int q = 0; q < 4; q++) {
        gh[q][0] = bhh[lane]; gh[q][1] = bhh[64 + lane]; gh[q][2] = bhh[128 + lane];
    }
#pragma unroll 4
    for (int k4 = 0; k4 < 16; k4++) {
        float4 w0v = *reinterpret_cast<const float4*>(&wsh[(k4 * 192 + lane) * 4]);
        float4 w1v = *reinterpret_cast<const float4*>(&wsh[(k4 * 192 + 64 + lane) * 4]);
        float4 w2v = *reinterpret_cast<const float4*>(&wsh[(k4 * 192 + 128 + lane) * 4]);
#pragma unroll
        for (int q = 0; q < 4; q++) {
            float4 h4 = *reinterpret_cast<const float4*>(&hb[w * 4 + q][k4 * 4]);
            gh[q][0] = fmaf(h4.x, w0v.x, gh[q][0]); gh[q][0] = fmaf(h4.y, w0v.y, gh[q][0]);
            gh[q][0] = fmaf(h4.z, w0v.z, gh[q][0]); gh[q][0] = fmaf(h4.w, w0v.w, gh[q][0]);
            gh[q][1] = fmaf(h4.x, w1v.x, gh[q][1]); gh[q][1] = fmaf(h4.y, w1v.y, gh[q][1]);
            gh[q][1] = fmaf(h4.z, w1v.z, gh[q][1]); gh[q][1] = fmaf(h4.w, w1v.w, gh[q][1]);
            gh[q][2] = fmaf(h4.x, w2v.x, gh[q][2]); gh[q][2] = fmaf(h4.y, w2v.y, gh[q][2]);
            gh[q][2] = fmaf(h4.z, w2v.z, gh[q][2]); gh[q][2] = fmaf(h4.w, w2v.w, gh[q][2]);
        }
    }

#pragma unroll
    for (int q = 0; q < 4; q++) {
        int n = base + w * 4 + q;
        if (n < N_NODES) {
            float hv = hb[w * 4 + q][lane];
            float r = sigm(gi[q][0] + gh[q][0]);
            float z = sigm(gi[q][1] + gh[q][1]);
            float nn = tanh_fast(gi[q][2] + r * gh[q][2]);
            float hnew = fmaxf((1.0f - z) * nn + z * hv, 0.0f);
            h[n * ND + lane] = hnew;
        }
    }
}

// fallback-path pooling
__global__ __launch_bounds__(256) void pool_kernel(
    const float* __restrict__ h, const int* __restrict__ batch,
    float* __restrict__ pool, float* __restrict__ cnt) {
    int idx = blockIdx.x * 256 + threadIdx.x;
    if (idx >= N_NODES * ND) return;
    int n = idx >> 6, f = idx & 63;
    int b = batch[n];
    ATOMIC_ADD_F32(&pool[b * ND + f], h[idx]);
    if (f == 0) ATOMIC_ADD_F32(&cnt[b], 1.0f);
}

__global__ __launch_bounds__(256) void readout_kernel(
    const float* __restrict__ pool, const float* __restrict__ cnt,
    const float* __restrict__ r0W, const float* __restrict__ r0b,
    const float* __restrict__ r1W, const float* __restrict__ r1b,
    float* __restrict__ out) {
    __shared__ float w0s[64 * 128];
    __shared__ float pb[4][64];
    int tid = threadIdx.x;
    for (int idx = tid; idx < 64 * 128; idx += 256) {
        int k = idx >> 7, j = idx & 127;
        w0s[((k >> 2) * 128 + j) * 4 + (k & 3)] = r0W[idx];
    }
    __syncthreads();
    int w = tid >> 6, lane = tid & 63;
    int g = blockIdx.x * 4 + w;
    float c = fmaxf(cnt[g], 1.0f);
    float pv = pool[g * ND + lane] / c;
    pb[w][lane] = pv;
    __syncthreads();

    float a0 = r0b[lane], a1 = r0b[64 + lane];
#pragma unroll
    for (int k4 = 0; k4 < 16; k4++) {
        float4 v = *reinterpret_cast<const float4*>(&pb[w][k4 * 4]);
        float4 qa = *reinterpret_cast<const float4*>(&w0s[(k4 * 128 + lane) * 4]);
        float4 qb = *reinterpret_cast<const float4*>(&w0s[(k4 * 128 + 64 + lane) * 4]);
        a0 = fmaf(v.x, qa.x, a0); a0 = fmaf(v.y, qa.y, a0);
        a0 = fmaf(v.z, qa.z, a0); a0 = fmaf(v.w, qa.w, a0);
        a1 = fmaf(v.x, qb.x, a1); a1 = fmaf(v.y, qb.y, a1);
        a1 = fmaf(v.z, qb.z, a1); a1 = fmaf(v.w, qb.w, a1);
    }
    a0 = fmaxf(a0, 0.0f);
    a1 = fmaxf(a1, 0.0f);
    float part = a0 * r1W[lane] + a1 * r1W[64 + lane];
#pragma unroll
    for (int off = 32; off > 0; off >>= 1) part += __shfl_down(part, off);
    if (lane == 0) out[g] = part + r1b[0];
}

// ---------------- fast path: deterministic pooling (batch is SORTED) ----------------

__global__ __launch_bounds__(256) void gptr_kernel(
    const int* __restrict__ batch, int* __restrict__ gptr) {
    int n = blockIdx.x * 256 + threadIdx.x;
    if (n >= N_NODES) return;
    int b = batch[n];
    int bp = (n == 0) ? -1 : batch[n - 1];
    for (int g = bp + 1; g <= b; g++) gptr[g] = n;
    if (n == N_NODES - 1)
        for (int g = b + 1; g <= N_GRAPHS; g++) gptr[g] = N_NODES;
}

__global__ __launch_bounds__(256) void pool_seg_kernel(
    const float* __restrict__ h, const int* __restrict__ gptr,
    float* __restrict__ pool) {
    int tid = threadIdx.x, w = tid >> 6, lane = tid & 63;
    int g = blockIdx.x * 4 + w;
    if (g >= N_GRAPHS) return;
    int rs = gptr[g], re = gptr[g + 1];
    float acc = 0.0f;
    for (int n = rs; n < re; n++) acc += h[(size_t)n * ND + lane];
    pool[(size_t)g * ND + lane] = acc;
}

__global__ __launch_bounds__(256) void readout2_kernel(
    const float* __restrict__ pool, const int* __restrict__ gptr,
    const float* __restrict__ r0W, const float* __restrict__ r0b,
    const float* __restrict__ r1W, const float* __restrict__ r1b,
    float* __restrict__ out) {
    __shared__ float w0s[64 * 128];
    __shared__ float pb[4][64];
    int tid = threadIdx.x;
    for (int idx = tid; idx < 64 * 128; idx += 256) {
        int k = idx >> 7, j = idx & 127;
        w0s[((k >> 2) * 128 + j) * 4 + (k & 3)] = r0W[idx];
    }
    __syncthreads();
    int w = tid >> 6, lane = tid & 63;
    int g = blockIdx.x * 4 + w;
    float c = fmaxf((float)(gptr[g + 1] - gptr[g]), 1.0f);
    float pv = pool[(size_t)g * ND + lane] / c;
    pb[w][lane] = pv;
    __syncthreads();

    float a0 = r0b[lane], a1 = r0b[64 + lane];
#pragma unroll
    for (int k4 = 0; k4 < 16; k4++) {
        float4 v = *reinterpret_cast<const float4*>(&pb[w][k4 * 4]);
        float4 qa = *reinterpret_cast<const float4*>(&w0s[(k4 * 128 + lane) * 4]);
        float4 qb = *reinterpret_cast<const float4*>(&w0s[(k4 * 128 + 64 + lane) * 4]);
        a0 = fmaf(v.x, qa.x, a0); a0 = fmaf(v.y, qa.y, a0);
        a0 = fmaf(v.z, qa.z, a0); a0 = fmaf(v.w, qa.w, a0);
        a1 = fmaf(v.x, qb.x, a1); a1 = fmaf(v.y, qb.y, a1);
        a1 = fmaf(v.z, qb.z, a1); a1 = fmaf(v.w, qb.w, a1);
    }
    a0 = fmaxf(a0, 0.0f);
    a1 = fmaxf(a1, 0.0f);
    float part = a0 * r1W[lane] + a1 * r1W[64 + lane];
#pragma unroll
    for (int off = 32; off > 0; off >>= 1) part += __shfl_down(part, off);
    if (lane == 0) out[g] = part + r1b[0];
}

// ---------------- old (fallback) msg path ----------------

__global__ __launch_bounds__(256) void wfrag_setup_kernel(
    const float* __restrict__ m0W, const float* __restrict__ m0b,
    const float* __restrict__ m1W,
    const float* __restrict__ eeW, const float* __restrict__ eeB,
    unsigned int* __restrict__ wf, float* __restrict__ b0p) {
    int l = blockIdx.x;
    int tid = threadIdx.x;
    const float* W0 = m0W + (size_t)l * 144 * 64;
    const float* W1 = m1W + (size_t)l * 64 * 64;
    unsigned int* base = wf + (size_t)l * WF_STRIDE;

    if (tid < 64) {
        float acc = m0b[l * 64 + tid];
#pragma unroll
        for (int kp = 0; kp < 16; kp++)
            acc = fmaf(eeB[kp], W0[(128 + kp) * 64 + tid], acc);
        b0p[l * 64 + tid] = acc;
    }

    for (int u = tid; u < 28 * 64; u += 256) {
        int slot = u >> 6, lane = u & 63;
        int g = lane >> 4, c16 = lane & 15;
        float w8[8];
        unsigned int* dsthi;
        unsigned int* dstlo;
        if (slot < 20) {
            int t = slot >> 2, n = slot & 3;
#pragma unroll
            for (int j = 0; j < 8; j++) {
                int k = 32 * t + 8 * g + j;
                float wv = 0.0f;
                if (t < 4) {
                    wv = W0[k * 64 + 16 * n + c16];
                } else if (g == 0 && j < 4) {
                    float a = 0.0f;
                    for (int kp = 0; kp < 16; kp++)
                        a = fmaf(eeW[j * 16 + kp], W0[(128 + kp) * 64 + 16 * n + c16], a);
                    wv = a;
                }
                w8[j] = wv;
            }
            dsthi = base + ((size_t)slot * 64 + lane) * 4;
            dstlo = base + 5120 + ((size_t)slot * 64 + lane) * 4;
        } else {
            int s2 = slot - 20;
#pragma unroll
            for (int j = 0; j < 8; j++) {
                int k = 32 * (s2 >> 2) + 8 * g + j;
                w8[j] = W1[k * 64 + 16 * (s2 & 3) + c16];
            }
            dsthi = base + 10240 + ((size_t)s2 * 64 + lane) * 4;
            dstlo = base + 12288 + ((size_t)s2 * 64 + lane) * 4;
        }
        unsigned int hi[4], lo[4];
        split8(w8, hi, lo);
#pragma unroll
        for (int i = 0; i < 4; i++) { dsthi[i] = hi[i]; dstlo[i] = lo[i]; }
    }
}

#define MSG_BLOCKS 1250
#define MSG_SLOTS (MSG_BLOCKS * 4)
#define MSG_ITERS 5
__global__ __launch_bounds__(256) void msg_mfma_kernel(
    const float* __restrict__ h, const int* __restrict__ ei, const int* __restrict__ ea,
    const unsigned int* __restrict__ wf, const float* __restrict__ b0p,
    const float* __restrict__ b1, float* __restrict__ agg) {
    __shared__ unsigned int mid[4][2048];
    const unsigned int* w0h = wf;
    const unsigned int* w0l = wf + 5120;
    const unsigned int* w1h = wf + 10240;
    const unsigned int* w1l = wf + 12288;
    int tid = threadIdx.x, w = tid >> 6, l = tid & 63, g = l >> 4, col = l & 15;
    unsigned int* midw = mid[w];

    float bias0v[4], bias1v[4];
#pragma unroll
    for (int n = 0; n < 4; n++) { bias0v[n] = b0p[16 * n + col]; bias1v[n] = b1[16 * n + col]; }

    int slot = blockIdx.x * 4 + w;
    for (int it = 0; it < MSG_ITERS; ++it) {
        int tb = (it * MSG_SLOTS + slot) * 32;
        int e0 = tb + col, e1 = e0 + 16;
        int s0 = ei[e0], s1 = ei[e1], d0 = ei[N_EDGES + e0], d1 = ei[N_EDGES + e1];
        int dr[2][4];
#pragma unroll
        for (int m = 0; m < 2; m++)
#pragma unroll
            for (int ri = 0; ri < 4; ri++)
                dr[m][ri] = ei[N_EDGES + tb + 16 * m + 4 * g + ri];

        unsigned int ah[4][2][4], alo[4][2][4];
        const float* ps[2] = { h + (size_t)s0 * 64, h + (size_t)s1 * 64 };
        const float* pd[2] = { h + (size_t)d0 * 64, h + (size_t)d1 * 64 };
#pragma unroll
        for (int t = 0; t < 4; t++) {
#pragma unroll
            for (int m = 0; m < 2; m++) {
                const float* p = (t < 2 ? ps[m] : pd[m]) + (t & 1) * 32 + 8 * g;
                f32x4 v0 = *reinterpret_cast<const f32x4*>(p);
                f32x4 v1 = *reinterpret_cast<const f32x4*>(p + 4);
                float v[8];
#pragma unroll
                for (int i = 0; i < 4; i++) { v[i] = v0[i]; v[4 + i] = v1[i]; }
                split8(v, ah[t][m], alo[t][m]);
            }
        }
        unsigned int a4[2][2];
        {
            int4 q0 = *reinterpret_cast<const int4*>(&ea[(size_t)e0 * 4]);
            int4 q1 = *reinterpret_cast<const int4*>(&ea[(size_t)e1 * 4]);
            a4[0][0] = g == 0 ? ((unsigned int)f2bf((float)q0.x) | ((unsigned int)f2bf((float)q0.y) << 16)) : 0u;
            a4[0][1] = g == 0 ? ((unsigned int)f2bf((float)q0.z) | ((unsigned int)f2bf((float)q0.w) << 16)) : 0u;
            a4[1][0] = g == 0 ? ((unsigned int)f2bf((float)q1.x) | ((unsigned int)f2bf((float)q1.y) << 16)) : 0u;
            a4[1][1] = g == 0 ? ((unsigned int)f2bf((float)q1.z) | ((unsigned int)f2bf((float)q1.w) << 16)) : 0u;
        }

        f32x4 acc[2][4];
#pragma unroll
        for (int m = 0; m < 2; m++)
#pragma unroll
            for (int n = 0; n < 4; n++) acc[m][n] = (f32x4)0.0f;
#pragma unroll
        for (int t = 0; t < 5; t++) {
#pragma unroll
            for (int n = 0; n < 4; n++) {
                uint4 bh = *reinterpret_cast<const uint4*>(&w0h[((size_t)(t * 4 + n) * 64 + l) * 4]);
                uint4 bl = *reinterpret_cast<const uint4*>(&w0l[((size_t)(t * 4 + n) * 64 + l) * 4]);
                short8 Bh = mk4(bh.x, bh.y, bh.z, bh.w);
                short8 Bl = mk4(bl.x, bl.y, bl.z, bl.w);
#pragma unroll
                for (int m = 0; m < 2; m++) {
                    short8 Ah, Al;
                    if (t < 4) {
                        Ah = mk4(ah[t][m][0], ah[t][m][1], ah[t][m][2], ah[t][m][3]);
                        Al = mk4(alo[t][m][0], alo[t][m][1], alo[t][m][2], alo[t][m][3]);
                    } else {
                        Ah = mk4(a4[m][0], a4[m][1], 0u, 0u);
                        Al = mk4(0u, 0u, 0u, 0u);
                    }
                    acc[m][n] = __builtin_amdgcn_mfma_f32_16x16x32_bf16(Ah, Bh, acc[m][n], 0, 0, 0);
                    acc[m][n] = __builtin_amdgcn_mfma_f32_16x16x32_bf16(Ah, Bl, acc[m][n], 0, 0, 0);
                    if (t < 4)
                        acc[m][n] = __builtin_amdgcn_mfma_f32_16x16x32_bf16(Al, Bh, acc[m][n], 0, 0, 0);
                }
            }
        }

#pragma unroll
        for (int m = 0; m < 2; m++)
#pragma unroll
            for (int n = 0; n < 4; n++)
#pragma unroll
                for (int ri = 0; ri < 4; ri++) {
                    float v = fmaxf(acc[m][n][ri] + bias0v[n], 0.0f);
                    unsigned short hh = f2bf(v);
                    unsigned short ll = f2bf(v - bf2f(hh));
                    int r = 16 * m + 4 * g + ri, c = 16 * n + col;
                    midw[r * 64 + (c ^ ((r & 7) << 2))] = (unsigned int)hh | ((unsigned int)ll << 16);
                }

        unsigned int a2h[2][2][4], a2l[2][2][4];
#pragma unroll
        for (int m = 0; m < 2; m++) {
            int r = col + 16 * m;
            int swz = (r & 7) << 2;
#pragma unroll
            for (int t2 = 0; t2 < 2; t2++) {
                int bc = 32 * t2 + 8 * g;
                uint4 q0 = *reinterpret_cast<const uint4*>(&midw[r * 64 + (bc ^ swz)]);
                uint4 q1 = *reinterpret_cast<const uint4*>(&midw[r * 64 + ((bc + 4) ^ swz)]);
                a2h[m][t2][0] = (q0.x & 0xFFFFu) | (q0.y << 16);
                a2l[m][t2][0] = (q0.x >> 16) | (q0.y & 0xFFFF0000u);
                a2h[m][t2][1] = (q0.z & 0xFFFFu) | (q0.w << 16);
                a2l[m][t2][1] = (q0.z >> 16) | (q0.w & 0xFFFF0000u);
                a2h[m][t2][2] = (q1.x & 0xFFFFu) | (q1.y << 16);
                a2l[m][t2][2] = (q1.x >> 16) | (q1.y & 0xFFFF0000u);
                a2h[m][t2][3] = (q1.z & 0xFFFFu) | (q1.w << 16);
                a2l[m][t2][3] = (q1.z >> 16) | (q1.w & 0xFFFF0000u);
            }
        }

        f32x4 acc2[2][4];
#pragma unroll
        for (int m = 0; m < 2; m++)
#pragma unroll
            for (int n = 0; n < 4; n++) acc2[m][n] = (f32x4)0.0f;
#pragma unroll
        for (int t2 = 0; t2 < 2; t2++) {
#pragma unroll
            for (int n = 0; n < 4; n++) {
                uint4 bh = *reinterpret_cast<const uint4*>(&w1h[((size_t)(t2 * 4 + n) * 64 + l) * 4]);
                uint4 bl = *reinterpret_cast<const uint4*>(&w1l[((size_t)(t2 * 4 + n) * 64 + l) * 4]);
                short8 Bh = mk4(bh.x, bh.y, bh.z, bh.w);
                short8 Bl = mk4(bl.x, bl.y, bl.z, bl.w);
#pragma unroll
                for (int m = 0; m < 2; m++) {
                    short8 Ah = mk4(a2h[m][t2][0], a2h[m][t2][1], a2h[m][t2][2], a2h[m][t2][3]);
                    short8 Al = mk4(a2l[m][t2][0], a2l[m][t2][1], a2l[m][t2][2], a2l[m][t2][3]);
                    acc2[m][n] = __builtin_amdgcn_mfma_f32_16x16x32_bf16(Ah, Bh, acc2[m][n], 0, 0, 0);
                    acc2[m][n] = __builtin_amdgcn_mfma_f32_16x16x32_bf16(Ah, Bl, acc2[m][n], 0, 0, 0);
                    acc2[m][n] = __builtin_amdgcn_mfma_f32_16x16x32_bf16(Al, Bh, acc2[m][n], 0, 0, 0);
                }
            }
        }

#pragma unroll
        for (int m = 0; m < 2; m++)
#pragma unroll
            for (int n = 0; n < 4; n++)
#pragma unroll
                for (int ri = 0; ri < 4; ri++) {
                    float v = acc2[m][n][ri] + bias1v[n];
                    ATOMIC_ADD_F32(&agg[(size_t)dr[m][ri] * 64 + 16 * n + col], v);
                }
    }
}

// ---------------- fast path: CSR build (deterministic) ----------------

__global__ __launch_bounds__(256) void hist_kernel(
    const int* __restrict__ ei, int* __restrict__ deg) {
    int e = blockIdx.x * 256 + threadIdx.x;
    if (e < N_EDGES) atomicAdd(&deg[ei[N_EDGES + e]], 1);
}

#define NCHUNK 196
__global__ __launch_bounds__(256) void scan1_kernel(
    const int* __restrict__ deg, int* __restrict__ rowptr, int* __restrict__ chunksum) {
    __shared__ int sb[256];
    int b = blockIdx.x, t = threadIdx.x, idx = b * 256 + t;
    int v = (idx < N_NODES) ? deg[idx] : 0;
    sb[t] = v;
    __syncthreads();
    for (int off = 1; off < 256; off <<= 1) {
        int x = (t >= off) ? sb[t - off] : 0;
        __syncthreads();
        sb[t] += x;
        __syncthreads();
    }
    if (idx < N_NODES) rowptr[idx] = sb[t] - v;
    if (t == 255) chunksum[b] = sb[255];
}

__global__ __launch_bounds__(256) void scan2_kernel(int* __restrict__ chunksum) {
    __shared__ int sb[256];
    int t = threadIdx.x;
    int v = (t < NCHUNK) ? chunksum[t] : 0;
    sb[t] = v;
    __syncthreads();
    for (int off = 1; off < 256; off <<= 1) {
        int x = (t >= off) ? sb[t - off] : 0;
        __syncthreads();
        sb[t] += x;
        __syncthreads();
    }
    if (t < NCHUNK) chunksum[t] = sb[t] - v;
}

__global__ __launch_bounds__(256) void scan3_kernel(
    int* __restrict__ rowptr, const int* __restrict__ chunksum, int* __restrict__ cursor) {
    int b = blockIdx.x, t = threadIdx.x, idx = b * 256 + t;
    if (idx < N_NODES) {
        int r = rowptr[idx] + chunksum[b];
        rowptr[idx] = r;
        cursor[idx] = r;
    }
    if (idx == 0) rowptr[N_NODES] = N_EDGES;
}

__global__ __launch_bounds__(256) void scatter_kernel(
    const int* __restrict__ ei, int* __restrict__ cursor, int* __restrict__ eids) {
    int e = blockIdx.x * 256 + threadIdx.x;
    if (e >= N_EDGES) return;
    int d = ei[N_EDGES + e];
    int p = atomicAdd(&cursor[d], 1);
    eids[p] = e;
}

// Wave-per-node bitonic sort (64 lanes) by edge id + parallel gather.
// Writes packed (attr_idx << 16) | src  (src < 65536, idx < 81).
__global__ __launch_bounds__(256) void sortseg_kernel(
    const int* __restrict__ rowptr, int* __restrict__ eids,
    const int* __restrict__ ei, const int* __restrict__ ea,
    unsigned int* __restrict__ spk) {
    int tid = threadIdx.x, lane = tid & 63;
    int n = blockIdx.x * 4 + (tid >> 6);
    if (n >= N_NODES) return;
    int rs = rowptr[n], re = rowptr[n + 1];
    int len = re - rs;
    if (len <= 0) return;

    if (len <= 64) {
        int key = (lane < len) ? eids[rs + lane] : 0x7FFFFFFF;
#pragma unroll
        for (int k = 2; k <= 64; k <<= 1) {
#pragma unroll
            for (int j = k >> 1; j > 0; j >>= 1) {
                int other = __shfl_xor(key, j);
                bool up = ((lane & k) == 0);
                bool lower = ((lane & j) == 0);
                key = ((lower == up) ? min(key, other) : max(key, other));
            }
        }
        if (lane < len) {
            int e = key;
            int4 q = *reinterpret_cast<const int4*>(&ea[(size_t)e * 4]);
            unsigned int idx = (unsigned int)(q.x + 3 * q.y + 9 * q.z + 27 * q.w);
            spk[rs + lane] = (unsigned int)ei[e] | (idx << 16);
        }
    } else {
        if (lane == 0) {
            for (int i = rs + 1; i < re; i++) {
                int k2 = eids[i];
                int j = i - 1;
                while (j >= rs && eids[j] > k2) { eids[j + 1] = eids[j]; j--; }
                eids[j + 1] = k2;
            }
        }
        __builtin_amdgcn_wave_barrier();
        for (int p = rs + lane; p < re; p += 64) {
            int e = eids[p];
            int4 q = *reinterpret_cast<const int4*>(&ea[(size_t)e * 4]);
            unsigned int idx = (unsigned int)(q.x + 3 * q.y + 9 * q.z + 27 * q.w);
            spk[p] = (unsigned int)ei[e] | (idx << 16);
        }
    }
}

// ---------------- fast path: weight prep ----------------

__global__ __launch_bounds__(256) void wsetup2_kernel(
    const float* __restrict__ m0W, const float* __restrict__ m0b,
    const float* __restrict__ m1W,
    const float* __restrict__ eeW, const float* __restrict__ eeB,
    unsigned int* __restrict__ wf2, float* __restrict__ Cbuf, float* __restrict__ b0p) {
    int l = blockIdx.x;
    int tid = threadIdx.x;
    const float* W0 = m0W + (size_t)l * 144 * 64;
    const float* W1 = m1W + (size_t)l * 64 * 64;
    unsigned int* base = wf2 + (size_t)l * WF2_STRIDE;

    if (tid < 64) {
        float acc = m0b[l * 64 + tid];
#pragma unroll
        for (int kp = 0; kp < 16; kp++)
            acc = fmaf(eeB[kp], W0[(128 + kp) * 64 + tid], acc);
        b0p[l * 64 + tid] = acc;
    }
    {
        int k = tid >> 6, f = tid & 63;
        float a = 0.0f;
#pragma unroll
        for (int kp = 0; kp < 16; kp++)
            a = fmaf(eeW[k * 16 + kp], W0[(128 + kp) * 64 + f], a);
        Cbuf[l * 256 + tid] = a;
    }
    for (int u = tid; u < 16 * 64; u += 256) {
        int slot = u >> 6, lane = u & 63;
        int g = lane >> 4, c16 = lane & 15;
        int t = slot >> 3, n = slot & 7;
        float w8[8];
#pragma unroll
        for (int j = 0; j < 8; j++) {
            int k = 32 * t + 8 * g + j;
            int col = 16 * n + c16;
            w8[j] = (col < 64) ? W0[k * 64 + col] : W0[(64 + k) * 64 + (col - 64)];
        }
        unsigned int hi[4], lo[4];
        split8(w8, hi, lo);
#pragma unroll
        for (int i = 0; i < 4; i++) {
            base[((size_t)slot * 64 + lane) * 4 + i] = hi[i];
            base[4096 + ((size_t)slot * 64 + lane) * 4 + i] = lo[i];
        }
    }
    for (int u = tid; u < 8 * 64; u += 256) {
        int slot = u >> 6, lane = u & 63;
        int g = lane >> 4, c16 = lane & 15;
        int t2 = slot >> 2, n2 = slot & 3;
        float w8[8];
#pragma unroll
        for (int j = 0; j < 8; j++)
            w8[j] = W1[(32 * t2 + 8 * g + j) * 64 + 16 * n2 + c16];
        unsigned int hi[4], lo[4];
        split8(w8, hi, lo);
#pragma unroll
        for (int i = 0; i < 4; i++) {
            base[8192 + ((size_t)slot * 64 + lane) * 4 + i] = hi[i];
            base[10240 + ((size_t)slot * 64 + lane) * 4 + i] = lo[i];
        }
    }
}

// LUT[l][idx][f] = sum_k digit_k(idx) * C[l][k][f], idx in [0,81)
__global__ __launch_bounds__(256) void lut_kernel(
    const float* __restrict__ Cbuf, float* __restrict__ LUT) {
    int id = blockIdx.x * 256 + threadIdx.x;
    if (id >= 3 * LUTN) return;
    int f = id & 63;
    int rest = id >> 6;
    int idx = rest % 81;
    int l = rest / 81;
    const float* C = Cbuf + l * 256;
    int i0 = idx % 3, i1 = (idx / 3) % 3, i2 = (idx / 9) % 3, i3 = idx / 27;
    float v = (float)i0 * C[f];
    v = fmaf((float)i1, C[64 + f], v);
    v = fmaf((float)i2, C[128 + f], v);
    v = fmaf((float)i3, C[192 + f], v);
    LUT[id] = v;
}

// P[l] = [W1; b1] @ Wih  (65 x 192 per layer), fully parallel.
#define PMAT_BLOCKS ((PN + 255) / 256)
__global__ __launch_bounds__(256) void pmat_kernel(
    const float* __restrict__ gWih, const float* __restrict__ m1W,
    const float* __restrict__ m1b, float* __restrict__ P) {
    int l = blockIdx.y;
    int idx = blockIdx.x * 256 + threadIdx.x;
    if (idx >= PN) return;
    int r = idx / 192, c = idx - r * 192;
    const float* Wih = gWih + (size_t)l * 64 * 192;
    const float* row = (r < 64) ? (m1W + (size_t)l * 64 * 64 + (size_t)r * 64)
                                : (m1b + (size_t)l * 64);
    float a = 0.0f;
    for (int q = 0; q < 64; q++) a = fmaf(row[q], Wih[q * 192 + c], a);
    P[(size_t)l * PN + idx] = a;
}

// GRU weight fragments with W1 folded; reads precomputed P.
__global__ __launch_bounds__(256) void wsetup3_kernel(
    const float* __restrict__ gbih, const float* __restrict__ gWhh,
    const float* __restrict__ gbhh, const float* __restrict__ P,
    unsigned int* __restrict__ wf3, float* __restrict__ bb) {
    int l = blockIdx.x;
    int tid = threadIdx.x;
    const float* Whh = gWhh + (size_t)l * 64 * 192;
    const float* bih = gbih + (size_t)l * 192;
    const float* bhh = gbhh + (size_t)l * 192;
    const float* Pl = P + (size_t)l * PN;
    unsigned int* base = wf3 + (size_t)l * GRU_STRIDE;

    for (int f = tid; f < 448; f += 256) {
        float v;
        if (f < 128) v = bih[f] + bhh[f];
        else if (f < 192) v = bih[f];
        else if (f < 256) v = bhh[f - 64];
        else if (f < 384) v = Pl[64 * 192 + (f - 256)];
        else v = Pl[64 * 192 + 128 + (f - 384)];
        bb[l * 512 + f] = v;
    }

    for (int u = tid; u < 48 * 64; u += 256) {
        int slot = u >> 6, lane = u & 63;
        int g = lane >> 4, c16 = lane & 15;
        float w8[8];
        unsigned int *dsthi, *dstlo;
        if (slot < 32) {
            int t = slot >> 3, n = slot & 7;
            int c = 16 * n + c16;
#pragma unroll
            for (int j = 0; j < 8; j++) {
                if (t < 2) {
                    int k = 32 * t + 8 * g + j;
                    w8[j] = Pl[k * 192 + c];
                } else {
                    int k = 32 * (t - 2) + 8 * g + j;
                    w8[j] = Whh[k * 192 + c];
                }
            }
            dsthi = base + ((size_t)slot * 64 + lane) * 4;
            dstlo = base + 8192 + ((size_t)slot * 64 + lane) * 4;
        } else if (slot < 40) {
            int s = slot - 32;
            int t = s >> 2, n = s & 3;
            int c = 128 + 16 * n + c16;
#pragma unroll
            for (int j = 0; j < 8; j++)
                w8[j] = Pl[(32 * t + 8 * g + j) * 192 + c];
            dsthi = base + 16384 + ((size_t)s * 64 + lane) * 4;
            dstlo = base + 18432 + ((size_t)s * 64 + lane) * 4;
        } else {
            int s = slot - 40;
            int t = s >> 2, n = s & 3;
            int c = 128 + 16 * n + c16;
#pragma unroll
            for (int j = 0; j < 8; j++)
                w8[j] = Whh[(32 * t + 8 * g + j) * 192 + c];
            dsthi = base + 20480 + ((size_t)s * 64 + lane) * 4;
            dstlo = base + 22528 + ((size_t)s * 64 + lane) * 4;
        }
        unsigned int hi[4], lo[4];
        split8(w8, hi, lo);
#pragma unroll
        for (int i = 0; i < 4; i++) { dsthi[i] = hi[i]; dstlo[i] = lo[i]; }
    }
}

// ---------------- fast path: per-layer kernels ----------------

#define PH_TILES ((N_NODES + 31) / 32)
__global__ __launch_bounds__(256) void ph_kernel(
    const float* __restrict__ h, const unsigned int* __restrict__ wf2,
    const float* __restrict__ b0p, float* __restrict__ Pa, float* __restrict__ Pb) {
    int tid = threadIdx.x, w = tid >> 6, l = tid & 63, g = l >> 4, c16 = l & 15;
    int tile = blockIdx.x * 4 + w;
    if (tile >= PH_TILES) return;
    int base = tile * 32;

    unsigned int ah[2][2][4], al_[2][2][4];
#pragma unroll
    for (int m = 0; m < 2; m++) {
        int row = base + 16 * m + c16;
        if (row >= N_NODES) row = N_NODES - 1;
#pragma unroll
        for (int t = 0; t < 2; t++) {
            const float* p = h + (size_t)row * 64 + 32 * t + 8 * g;
            f32x4 v0 = *reinterpret_cast<const f32x4*>(p);
            f32x4 v1 = *reinterpret_cast<const f32x4*>(p + 4);
            float v[8];
#pragma unroll
            for (int i = 0; i < 4; i++) { v[i] = v0[i]; v[4 + i] = v1[i]; }
            split8(v, ah[m][t], al_[m][t]);
        }
    }

    f32x4 acc[2][8];
#pragma unroll
    for (int m = 0; m < 2; m++)
#pragma unroll
        for (int n = 0; n < 8; n++) acc[m][n] = (f32x4)0.0f;

    const unsigned int* wh = wf2;
    const unsigned int* wl = wf2 + 4096;
#pragma unroll
    for (int t = 0; t < 2; t++) {
#pragma unroll
        for (int n = 0; n < 8; n++) {
            int slot = t * 8 + n;
            uint4 bh = *reinterpret_cast<const uint4*>(&wh[((size_t)slot * 64 + l) * 4]);
            uint4 bl = *reinterpret_cast<const uint4*>(&wl[((size_t)slot * 64 + l) * 4]);
            short8 Bh = mk4(bh.x, bh.y, bh.z, bh.w);
            short8 Bl = mk4(bl.x, bl.y, bl.z, bl.w);
#pragma unroll
            for (int m = 0; m < 2; m++) {
                short8 Ah = mk4(ah[m][t][0], ah[m][t][1], ah[m][t][2], ah[m][t][3]);
                short8 Al = mk4(al_[m][t][0], al_[m][t][1], al_[m][t][2], al_[m][t][3]);
                acc[m][n] = __builtin_amdgcn_mfma_f32_16x16x32_bf16(Ah, Bh, acc[m][n], 0, 0, 0);
                acc[m][n] = __builtin_amdgcn_mfma_f32_16x16x32_bf16(Ah, Bl, acc[m][n], 0, 0, 0);
                acc[m][n] = __builtin_amdgcn_mfma_f32_16x16x32_bf16(Al, Bh, acc[m][n], 0, 0, 0);
            }
        }
    }

#pragma unroll
    for (int m = 0; m < 2; m++)
#pragma unroll
        for (int n = 0; n < 8; n++)
#pragma unroll
            for (int ri = 0; ri < 4; ri++) {
                int row = base + 16 * m + 4 * g + ri;
                if (row < N_NODES) {
                    if (n < 4)
                        Pa[(size_t)row * 64 + 16 * n + c16] = acc[m][n][ri];
                    else
                        Pb[(size_t)row * 64 + 16 * (n - 4) + c16] =
                            acc[m][n][ri] + b0p[16 * (n - 4) + c16];
                }
            }
}

// Edge aggregation, XCD-strip partitioned: 16-lane groups, strip = blockIdx&3
// (XCD k gets blocks k, k+8, ... all with strip k%4 -> per-XCD Pa footprint
// = 50000 x 64B = 3.2 MB < 4 MB L2). Same ascending-p sum order -> bitwise identical.
#define AGG_BLOCKS 4096
__global__ __launch_bounds__(256) void agg_edge_kernel(
    const float* __restrict__ Pa, const float* __restrict__ Pb,
    const unsigned int* __restrict__ spk, const int* __restrict__ rowptr,
    const float* __restrict__ LUT, float* __restrict__ aggmid) {
    int tid = threadIdx.x;
    int l16 = tid & 15;
    int strip = blockIdx.x & 3;
    int fo = strip * 16 + l16;
    int gid = (blockIdx.x >> 2) * 16 + (tid >> 4);
    const int ngrp = (AGG_BLOCKS >> 2) * 16;

    for (int n = gid; n < N_NODES; n += ngrp) {
        int rs = rowptr[n], re = rowptr[n + 1];
        float pbv = Pb[(size_t)n * 64 + fo];
        float acc = 0.0f;
        int p = rs;
        for (; p + 16 <= re; p += 16) {
            unsigned int u[16];
#pragma unroll
            for (int i = 0; i < 16; i++) u[i] = spk[p + i];
            float pav[16], lv[16];
#pragma unroll
            for (int i = 0; i < 16; i++)
                pav[i] = Pa[(size_t)(u[i] & 0xFFFFu) * 64 + fo];
#pragma unroll
            for (int i = 0; i < 16; i++)
                lv[i] = LUT[(size_t)(u[i] >> 16) * 64 + fo];
#pragma unroll
            for (int i = 0; i < 16; i++)
                acc += fmaxf(pav[i] + pbv + lv[i], 0.0f);
        }
        for (; p + 8 <= re; p += 8) {
            unsigned int u[8];
#pragma unroll
            for (int i = 0; i < 8; i++) u[i] = spk[p + i];
            float pav[8], lv[8];
#pragma unroll
            for (int i = 0; i < 8; i++)
                pav[i] = Pa[(size_t)(u[i] & 0xFFFFu) * 64 + fo];
#pragma unroll
            for (int i = 0; i < 8; i++)
                lv[i] = LUT[(size_t)(u[i] >> 16) * 64 + fo];
#pragma unroll
            for (int i = 0; i < 8; i++)
                acc += fmaxf(pav[i] + pbv + lv[i], 0.0f);
        }
        for (; p < re; ++p) {
            unsigned int u = spk[p];
            float v = Pa[(size_t)(u & 0xFFFFu) * 64 + fo] + pbv +
                      LUT[(size_t)(u >> 16) * 64 + fo];
            acc += fmaxf(v, 0.0f);
        }
        aggmid[(size_t)n * 64 + fo] = acc;
    }
}

// MFMA GRU with W1 folded: A t=0,1 = aggmid, t=2,3 = h. deg-scaled bias in epilogue.
__global__ __launch_bounds__(256) void gru_mfma2_kernel(
    float* __restrict__ h, const float* __restrict__ aggmid,
    const int* __restrict__ deg,
    const unsigned int* __restrict__ wf3, const float* __restrict__ bb) {
    int tid = threadIdx.x, w = tid >> 6, l = tid & 63, g = l >> 4, c16 = l & 15;
    int tile = blockIdx.x * 4 + w;
    if (tile >= PH_TILES) return;
    int base = tile * 32;

    unsigned int aAh[2][2][4], aAl[2][2][4];
    unsigned int hAh[2][2][4], hAl[2][2][4];
#pragma unroll
    for (int m = 0; m < 2; m++) {
        int row = base + 16 * m + c16;
        if (row >= N_NODES) row = N_NODES - 1;
#pragma unroll
        for (int t = 0; t < 2; t++) {
            const float* pa = aggmid + (size_t)row * 64 + 32 * t + 8 * g;
            const float* ph = h + (size_t)row * 64 + 32 * t + 8 * g;
            f32x4 va0 = *reinterpret_cast<const f32x4*>(pa);
            f32x4 va1 = *reinterpret_cast<const f32x4*>(pa + 4);
            f32x4 vh0 = *reinterpret_cast<const f32x4*>(ph);
            f32x4 vh1 = *reinterpret_cast<const f32x4*>(ph + 4);
            float v[8];
#pragma unroll
            for (int i = 0; i < 4; i++) { v[i] = va0[i]; v[4 + i] = va1[i]; }
            split8(v, aAh[m][t], aAl[m][t]);
#pragma unroll
            for (int i = 0; i < 4; i++) { v[i] = vh0[i]; v[4 + i] = vh1[i]; }
            split8(v, hAh[m][t], hAl[m][t]);
        }
    }

    f32x4 accS[2][8];
#pragma unroll
    for (int m = 0; m < 2; m++)
#pragma unroll
        for (int n = 0; n < 8; n++) accS[m][n] = (f32x4)0.0f;
#pragma unroll
    for (int t = 0; t < 4; t++) {
#pragma unroll
        for (int n = 0; n < 8; n++) {
            int slot = t * 8 + n;
            uint4 bh = *reinterpret_cast<const uint4*>(&wf3[((size_t)slot * 64 + l) * 4]);
            uint4 bl = *reinterpret_cast<const uint4*>(&wf3[8192 + ((size_t)slot * 64 + l) * 4]);
            short8 Bh = mk4(bh.x, bh.y, bh.z, bh.w);
            short8 Bl = mk4(bl.x, bl.y, bl.z, bl.w);
#pragma unroll
            for (int m = 0; m < 2; m++) {
                const unsigned int* uh = (t < 2) ? aAh[m][t] : hAh[m][t - 2];
                const unsigned int* ul = (t < 2) ? aAl[m][t] : hAl[m][t - 2];
                short8 Ah = mk4(uh[0], uh[1], uh[2], uh[3]);
                short8 Al = mk4(ul[0], ul[1], ul[2], ul[3]);
                accS[m][n] = __builtin_amdgcn_mfma_f32_16x16x32_bf16(Ah, Bh, accS[m][n], 0, 0, 0);
                accS[m][n] = __builtin_amdgcn_mfma_f32_16x16x32_bf16(Ah, Bl, accS[m][n], 0, 0, 0);
                accS[m][n] = __builtin_amdgcn_mfma_f32_16x16x32_bf16(Al, Bh, accS[m][n], 0, 0, 0);
            }
        }
    }

    f32x4 accI[2][4], accH[2][4];
#pragma unroll
    for (int m = 0; m < 2; m++)
#pragma unroll
        for (int n = 0; n < 4; n++) { accI[m][n] = (f32x4)0.0f; accH[m][n] = (f32x4)0.0f; }
#pragma unroll
    for (int t = 0; t < 2; t++) {
#pragma unroll
        for (int n = 0; n < 4; n++) {
            int s = t * 4 + n;
            uint4 bhi = *reinterpret_cast<const uint4*>(&wf3[16384 + ((size_t)s * 64 + l) * 4]);
            uint4 bli = *reinterpret_cast<const uint4*>(&wf3[18432 + ((size_t)s * 64 + l) * 4]);
            uint4 bhh = *reinterpret_cast<const uint4*>(&wf3[20480 + ((size_t)s * 64 + l) * 4]);
            uint4 blh = *reinterpret_cast<const uint4*>(&wf3[22528 + ((size_t)s * 64 + l) * 4]);
            short8 BhI = mk4(bhi.x, bhi.y, bhi.z, bhi.w);
            short8 BlI = mk4(bli.x, bli.y, bli.z, bli.w);
            short8 BhH = mk4(bhh.x, bhh.y, bhh.z, bhh.w);
            short8 BlH = mk4(blh.x, blh.y, blh.z, blh.w);
#pragma unroll
            for (int m = 0; m < 2; m++) {
                short8 Ah = mk4(aAh[m][t][0], aAh[m][t][1], aAh[m][t][2], aAh[m][t][3]);
                short8 Al = mk4(aAl[m][t][0], aAl[m][t][1], aAl[m][t][2], aAl[m][t][3]);
                accI[m][n] = __builtin_amdgcn_mfma_f32_16x16x32_bf16(Ah, BhI, accI[m][n], 0, 0, 0);
                accI[m][n] = __builtin_amdgcn_mfma_f32_16x16x32_bf16(Ah, BlI, accI[m][n], 0, 0, 0);
                accI[m][n] = __builtin_amdgcn_mfma_f32_16x16x32_bf16(Al, BhI, accI[m][n], 0, 0, 0);
                short8 Hh = mk4(hAh[m][t][0], hAh[m][t][1], hAh[m][t][2], hAh[m][t][3]);
                short8 Hl = mk4(hAl[m][t][0], hAl[m][t][1], hAl[m][t][2], hAl[m][t][3]);
                accH[m][n] = __builtin_amdgcn_mfma_f32_16x16x32_bf16(Hh, BhH, accH[m][n], 0, 0, 0);
                accH[m][n] = __builtin_amdgcn_mfma_f32_16x16x32_bf16(Hh, BlH, accH[m][n], 0, 0, 0);
                accH[m][n] = __builtin_amdgcn_mfma_f32_16x16x32_bf16(Hl, BhH, accH[m][n], 0, 0, 0);
            }
        }
    }

#pragma unroll
    for (int m = 0; m < 2; m++)
#pragma unroll
        for (int ri = 0; ri < 4; ri++) {
            int row = base + 16 * m + 4 * g + ri;
            if (row < N_NODES) {
                float dv = (float)deg[row];
#pragma unroll
                for (int n = 0; n < 4; n++) {
                    int f = 16 * n + c16;
                    float r = sigm(accS[m][n][ri] + bb[f] + dv * bb[256 + f]);
                    float z = sigm(accS[m][4 + n][ri] + bb[64 + f] + dv * bb[256 + 64 + f]);
                    float ninn = accI[m][n][ri] + bb[128 + f] + dv * bb[384 + f];
                    float nh = accH[m][n][ri] + bb[192 + f];
                    float nn = tanh_fast(ninn + r * nh);
                    float hv = h[(size_t)row * 64 + f];
                    h[(size_t)row * 64 + f] = fmaxf((1.0f - z) * nn + z * hv, 0.0f);
                }
            }
        }
}

// ---------------- launch ----------------

extern "C" void kernel_launch(void* const* d_in, const int* in_sizes, int n_in,
                              void* d_out, int out_size, void* d_ws, size_t ws_size,
                              hipStream_t stream) {
    const int* x = (const int*)d_in[0];
    const int* ei = (const int*)d_in[1];
    const int* ea = (const int*)d_in[2];
    const int* batch = (const int*)d_in[3];
    const float* neW = (const float*)d_in[4];
    const float* neB = (const float*)d_in[5];
    const float* eeW = (const float*)d_in[6];
    const float* eeB = (const float*)d_in[7];
    const float* m0W = (const float*)d_in[8];
    const float* m0b = (const float*)d_in[9];
    const float* m1W = (const float*)d_in[10];
    const float* m1b = (const float*)d_in[11];
    const float* gWih = (const float*)d_in[12];
    const float* gbih = (const float*)d_in[13];
    const float* gWhh = (const float*)d_in[14];
    const float* gbhh = (const float*)d_in[15];
    const float* r0W = (const float*)d_in[16];
    const float* r0b = (const float*)d_in[17];
    const float* r1W = (const float*)d_in[18];
    const float* r1b = (const float*)d_in[19];

    float* ws = (float*)d_ws;

    const size_t OFF_H = 0;
    const size_t OFF_PA = 3200000;      // Pa; also temp eids during CSR build
    const size_t OFF_PB = 6400000;
    const size_t OFF_AGGMID = 9600000;
    const size_t OFF_SSORT = 12800000;  // packed (idx<<16|src)
    const size_t OFF_EAPK = 13600000;   // unused (kept for layout stability)
    const size_t OFF_DEG = 14400000;
    const size_t OFF_ROWPTR = 14460000;
    const size_t OFF_CURSOR = 14520000;
    const size_t OFF_CHUNK = 14580000;
    const size_t OFF_WF2 = 14590000;
    const size_t OFF_C = 14630000;
    const size_t OFF_B0P = 14631000;
    const size_t OFF_POOL = 14640000;   // pool (after layers); wf3+bb+Ptmp+LUT during setup/layers
    const size_t OFF_GPTR = 14780000;   // N_GRAPHS+1 ints
    const size_t FAST_F32 = 14790000;

    bool fast = ws_size >= FAST_F32 * sizeof(float);

    if (fast) {
        float* h = ws + OFF_H;
        float* Pa = ws + OFF_PA;
        float* Pb = ws + OFF_PB;
        float* aggmid = ws + OFF_AGGMID;
        int* eids = (int*)(ws + OFF_PA);   // temp during CSR build (before Pa live)
        unsigned int* spk = (unsigned int*)(ws + OFF_SSORT);
        int* deg = (int*)(ws + OFF_DEG);
        int* rowptr = (int*)(ws + OFF_ROWPTR);
        int* cursor = (int*)(ws + OFF_CURSOR);
        int* chunksum = (int*)(ws + OFF_CHUNK);
        unsigned int* wf2 = (unsigned int*)(ws + OFF_WF2);
        float* Cbuf = ws + OFF_C;
        float* b0p = ws + OFF_B0P;
        float* pool = ws + OFF_POOL;
        unsigned int* wf3 = (unsigned int*)(ws + OFF_POOL);       // 73728 u32
        float* bb = ws + OFF_POOL + 73728;                        // 1536 f32
        float* Ptmp = ws + OFF_POOL + 73728 + 1536;               // 3*PN f32
        float* lut = ws + OFF_POOL + 73728 + 1536 + 3 * PN;       // 3*LUTN f32
        int* gptr = (int*)(ws + OFF_GPTR);

        node_enc_kernel<<<(N_NODES * ND + 255) / 256, 256, 0, stream>>>(x, neW, neB, h);
        wsetup2_kernel<<<3, 256, 0, stream>>>(m0W, m0b, m1W, eeW, eeB, wf2, Cbuf, b0p);
        lut_kernel<<<(3 * LUTN + 255) / 256, 256, 0, stream>>>(Cbuf, lut);
        pmat_kernel<<<dim3(PMAT_BLOCKS, 3), 256, 0, stream>>>(gWih, m1W, m1b, Ptmp);
        wsetup3_kernel<<<3, 256, 0, stream>>>(gbih, gWhh, gbhh, Ptmp, wf3, bb);
        gptr_kernel<<<(N_NODES + 255) / 256, 256, 0, stream>>>(batch, gptr);

        hipMemsetAsync(deg, 0, N_NODES * sizeof(int), stream);
        hist_kernel<<<(N_EDGES + 255) / 256, 256, 0, stream>>>(ei, deg);
        scan1_kernel<<<NCHUNK, 256, 0, stream>>>(deg, rowptr, chunksum);
        scan2_kernel<<<1, 256, 0, stream>>>(chunksum);
        scan3_kernel<<<NCHUNK, 256, 0, stream>>>(rowptr, chunksum, cursor);
        scatter_kernel<<<(N_EDGES + 255) / 256, 256, 0, stream>>>(ei, cursor, eids);
        sortseg_kernel<<<(N_NODES + 3) / 4, 256, 0, stream>>>(rowptr, eids, ei, ea, spk);

        for (int l = 0; l < NL; l++) {
            ph_kernel<<<(PH_TILES + 3) / 4, 256, 0, stream>>>(
                h, wf2 + (size_t)l * WF2_STRIDE, b0p + l * 64, Pa, Pb);
            agg_edge_kernel<<<AGG_BLOCKS, 256, 0, stream>>>(
                Pa, Pb, spk, rowptr, lut + (size_t)l * LUTN, aggmid);
            gru_mfma2_kernel<<<(PH_TILES + 3) / 4, 256, 0, stream>>>(
                h, aggmid, deg, wf3 + (size_t)l * GRU_STRIDE, bb + (size_t)l * 512);
        }

        pool_seg_kernel<<<N_GRAPHS / 4, 256, 0, stream>>>(h, gptr, pool);
        readout2_kernel<<<N_GRAPHS / 4, 256, 0, stream>>>(pool, gptr, r0W, r0b, r1W, r1b,
                                                          (float*)d_out);
    } else {
        // round-4 fallback (fits in 26.2 MB)
        float* h = ws;
        float* agg = ws + 3200000;
        float* pool = ws + 6400000;
        float* cnt = ws + 6400000 + 131072;
        unsigned int* wfBase = (unsigned int*)(ws + 6400000);
        float* b0pBase = ws + 6400000 + 43008;

        node_enc_kernel<<<(N_NODES * ND + 255) / 256, 256, 0, stream>>>(x, neW, neB, h);
        wfrag_setup_kernel<<<3, 256, 0, stream>>>(m0W, m0b, m1W, eeW, eeB, wfBase, b0pBase);

        for (int l = 0; l < NL; l++) {
            hipMemsetAsync(agg, 0, (size_t)N_NODES * ND * sizeof(float), stream);
            msg_mfma_kernel<<<MSG_BLOCKS, 256, 0, stream>>>(
                h, ei, ea, wfBase + (size_t)l * WF_STRIDE, b0pBase + l * 64,
                m1b + (size_t)l * 64, agg);
            gru_kernel<<<(N_NODES + 15) / 16, 256, 0, stream>>>(
                h, agg,
                gWih + (size_t)l * 64 * 192, gbih + (size_t)l * 192,
                gWhh + (size_t)l * 64 * 192, gbhh + (size_t)l * 192);
        }

        hipMemsetAsync(pool, 0, (size_t)(N_GRAPHS * ND + N_GRAPHS) * sizeof(float), stream);
        pool_kernel<<<(N_NODES * ND + 255) / 256, 256, 0, stream>>>(h, batch, pool, cnt);
        readout_kernel<<<N_GRAPHS / 4, 256, 0, stream>>>(pool, cnt, r0W, r0b, r1W, r1b,
                                                         (float*)d_out);
    }
}

// Round 15
// 427.516 us; speedup vs baseline: 1.1473x; 1.1473x over previous
//
#include <hip/hip_runtime.h>

#define N_NODES 50000
#define N_EDGES 800000
#define N_GRAPHS 2048
#define ND 64
#define NL 3
#define WF_STRIDE 14336   // old path u32 per layer
#define WF2_STRIDE 12288  // fast path u32 per layer: w0ab hi 4096 | lo 4096 | w1 hi 2048 | lo 2048
#define GRU_STRIDE 24576  // gru frags u32 per layer
#define PN (65 * 192)     // P temp per layer: rows 0..63 = W1@Wih, row 64 = b1@Wih
#define LUTN (81 * 64)    // per-layer edge-attr LUT

#define ATOMIC_ADD_F32(p, v) unsafeAtomicAdd((p), (v))

typedef __attribute__((ext_vector_type(8))) short short8;
typedef __attribute__((ext_vector_type(4))) float f32x4;

union Frag { unsigned int u[4]; short8 s; };

__device__ __forceinline__ short8 mk4(unsigned int a, unsigned int b,
                                      unsigned int c, unsigned int d) {
    Frag f; f.u[0] = a; f.u[1] = b; f.u[2] = c; f.u[3] = d; return f.s;
}

__device__ __forceinline__ float bf2f(unsigned short u) {
    return __uint_as_float(((unsigned int)u) << 16);
}
__device__ __forceinline__ unsigned short f2bf(float f) {
    unsigned int u = __float_as_uint(f);
    unsigned int r = (u + 0x7FFFu + ((u >> 16) & 1u)) >> 16;
    return (unsigned short)r;
}
__device__ __forceinline__ float sigm(float x) { return 1.0f / (1.0f + __expf(-x)); }
__device__ __forceinline__ float tanh_fast(float x) {
    float ax = fabsf(x);
    float e = __expf(-2.0f * ax);
    float t = (1.0f - e) / (1.0f + e);
    return copysignf(t, x);
}

__device__ __forceinline__ void split8(const float* v, unsigned int* hi, unsigned int* lo) {
#pragma unroll
    for (int i = 0; i < 4; i++) {
        float a = v[2 * i], b = v[2 * i + 1];
        unsigned short ah = f2bf(a), bh = f2bf(b);
        unsigned short al = f2bf(a - bf2f(ah));
        unsigned short bl = f2bf(b - bf2f(bh));
        hi[i] = (unsigned int)ah | ((unsigned int)bh << 16);
        lo[i] = (unsigned int)al | ((unsigned int)bl << 16);
    }
}

// ---------------- shared kernels ----------------

__global__ __launch_bounds__(256) void node_enc_kernel(
    const int* __restrict__ x, const float* __restrict__ W,
    const float* __restrict__ b, float* __restrict__ h) {
    int idx = blockIdx.x * 256 + threadIdx.x;
    if (idx >= N_NODES * ND) return;
    int n = idx >> 6, f = idx & 63;
    float acc = b[f];
#pragma unroll
    for (int k = 0; k < 9; k++)
        acc = fmaf((float)x[n * 9 + k], W[k * ND + f], acc);
    h[idx] = acc;
}

// fallback GRU (LDS-staged VALU version)
__global__ __launch_bounds__(256) void gru_kernel(
    float* __restrict__ h, const float* __restrict__ agg,
    const float* __restrict__ Wih, const float* __restrict__ bih,
    const float* __restrict__ Whh, const float* __restrict__ bhh) {
    __shared__ float wsh[64 * 192];
    __shared__ float ab[16][64], hb[16][64];

    int tid = threadIdx.x, w = tid >> 6, lane = tid & 63;
    int base = blockIdx.x * 16;

#pragma unroll
    for (int q = 0; q < 4; q++) {
        int n = base + w * 4 + q;
        int n0 = n < N_NODES ? n : 0;
        ab[w * 4 + q][lane] = agg[n0 * ND + lane];
        hb[w * 4 + q][lane] = h[n0 * ND + lane];
    }
    for (int idx = tid; idx < 64 * 192; idx += 256) {
        int k = idx / 192, j = idx - k * 192;
        wsh[((k >> 2) * 192 + j) * 4 + (k & 3)] = Wih[idx];
    }
    __syncthreads();

    float gi[4][3];
#pragma unroll
    for (int q = 0; q < 4; q++) {
        gi[q][0] = bih[lane]; gi[q][1] = bih[64 + lane]; gi[q][2] = bih[128 + lane];
    }
#pragma unroll 4
    for (int k4 = 0; k4 < 16; k4++) {
        float4 w0v = *reinterpret_cast<const float4*>(&wsh[(k4 * 192 + lane) * 4]);
        float4 w1v = *reinterpret_cast<const float4*>(&wsh[(k4 * 192 + 64 + lane) * 4]);
        float4 w2v = *reinterpret_cast<const float4*>(&wsh[(k4 * 192 + 128 + lane) * 4]);
#pragma unroll
        for (int q = 0; q < 4; q++) {
            float4 a4 = *reinterpret_cast<const float4*>(&ab[w * 4 + q][k4 * 4]);
            gi[q][0] = fmaf(a4.x, w0v.x, gi[q][0]); gi[q][0] = fmaf(a4.y, w0v.y, gi[q][0]);
            gi[q][0] = fmaf(a4.z, w0v.z, gi[q][0]); gi[q][0] = fmaf(a4.w, w0v.w, gi[q][0]);
            gi[q][1] = fmaf(a4.x, w1v.x, gi[q][1]); gi[q][1] = fmaf(a4.y, w1v.y, gi[q][1]);
            gi[q][1] = fmaf(a4.z, w1v.z, gi[q][1]); gi[q][1] = fmaf(a4.w, w1v.w, gi[q][1]);
            gi[q][2] = fmaf(a4.x, w2v.x, gi[q][2]); gi[q][2] = fmaf(a4.y, w2v.y, gi[q][2]);
            gi[q][2] = fmaf(a4.z, w2v.z, gi[q][2]); gi[q][2] = fmaf(a4.w, w2v.w, gi[q][2]);
        }
    }
    __syncthreads();
    for (int idx = tid; idx < 64 * 192; idx += 256) {
        int k = idx / 192, j = idx - k * 192;
        wsh[((k >> 2) * 192 + j) * 4 + (k & 3)] = Whh[idx];
    }
    __syncthreads();

    float gh[4][3];
#pragma unroll
    for (int q = 0; q < 4; q++) {
        gh[q][0] = bhh[lane]; gh[q][1] = bhh[64 + lane]; gh[q][2] = bhh[128 + lane];
    }
#pragma unroll 4
    for (int k4 = 0; k4 < 16; k4++) {
        float4 w0v = *reinterpret_cast<const float4*>(&wsh[(k4 * 192 + lane) * 4]);
        float4 w1v = *reinterpret_cast<const float4*>(&wsh[(k4 * 192 + 64 + lane) * 4]);
        float4 w2v = *reinterpret_cast<const float4*>(&wsh[(k4 * 192 + 128 + lane) * 4]);
#pragma unroll
        for (int q = 0; q < 4; q++) {
            float4 h4 = *reinterpret_cast<const float4*>(&hb[w * 4 + q][k4 * 4]);
            gh[q][0] = fmaf(h4.x, w0v.x, gh[q][0]); gh[q][0] = fmaf(h4.y, w0v.y, gh[q][0]);
            gh[q][0] = fmaf(h4.z, w0v.z, gh[q][0]); gh[q][0] = fmaf(h4.w, w0v.w, gh[q][0]);
            gh[q][1] = fmaf(h4.x, w1v.x, gh[q][1]); gh[q][1] = fmaf(h4.y, w1v.y, gh[q][1]);
            gh[q][1] = fmaf(h4.z, w1v.z, gh[q][1]); gh[q][1] = fmaf(h4.w, w1v.w, gh[q][1]);
            gh[q][2] = fmaf(h4.x, w2v.x, gh[q][2]); gh[q][2] = fmaf(h4.y, w2v.y, gh[q][2]);
            gh[q][2] = fmaf(h4.z, w2v.z, gh[q][2]); gh[q][2] = fmaf(h4.w, w2v.w, gh[q][2]);
        }
    }

#pragma unroll
    for (int q = 0; q < 4; q++) {
        int n = base + w * 4 + q;
        if (n < N_NODES) {
            float hv = hb[w * 4 + q][lane];
            float r = sigm(gi[q][0] + gh[q][0]);
            float z = sigm(gi[q][1] + gh[q][1]);
            float nn = tanh_fast(gi[q][2] + r * gh[q][2]);
            float hnew = fmaxf((1.0f - z) * nn + z * hv, 0.0f);
            h[n * ND + lane] = hnew;
        }
    }
}

// fallback-path pooling
__global__ __launch_bounds__(256) void pool_kernel(
    const float* __restrict__ h, const int* __restrict__ batch,
    float* __restrict__ pool, float* __restrict__ cnt) {
    int idx = blockIdx.x * 256 + threadIdx.x;
    if (idx >= N_NODES * ND) return;
    int n = idx >> 6, f = idx & 63;
    int b = batch[n];
    ATOMIC_ADD_F32(&pool[b * ND + f], h[idx]);
    if (f == 0) ATOMIC_ADD_F32(&cnt[b], 1.0f);
}

__global__ __launch_bounds__(256) void readout_kernel(
    const float* __restrict__ pool, const float* __restrict__ cnt,
    const float* __restrict__ r0W, const float* __restrict__ r0b,
    const float* __restrict__ r1W, const float* __restrict__ r1b,
    float* __restrict__ out) {
    __shared__ float w0s[64 * 128];
    __shared__ float pb[4][64];
    int tid = threadIdx.x;
    for (int idx = tid; idx < 64 * 128; idx += 256) {
        int k = idx >> 7, j = idx & 127;
        w0s[((k >> 2) * 128 + j) * 4 + (k & 3)] = r0W[idx];
    }
    __syncthreads();
    int w = tid >> 6, lane = tid & 63;
    int g = blockIdx.x * 4 + w;
    float c = fmaxf(cnt[g], 1.0f);
    float pv = pool[g * ND + lane] / c;
    pb[w][lane] = pv;
    __syncthreads();

    float a0 = r0b[lane], a1 = r0b[64 + lane];
#pragma unroll
    for (int k4 = 0; k4 < 16; k4++) {
        float4 v = *reinterpret_cast<const float4*>(&pb[w][k4 * 4]);
        float4 qa = *reinterpret_cast<const float4*>(&w0s[(k4 * 128 + lane) * 4]);
        float4 qb = *reinterpret_cast<const float4*>(&w0s[(k4 * 128 + 64 + lane) * 4]);
        a0 = fmaf(v.x, qa.x, a0); a0 = fmaf(v.y, qa.y, a0);
        a0 = fmaf(v.z, qa.z, a0); a0 = fmaf(v.w, qa.w, a0);
        a1 = fmaf(v.x, qb.x, a1); a1 = fmaf(v.y, qb.y, a1);
        a1 = fmaf(v.z, qb.z, a1); a1 = fmaf(v.w, qb.w, a1);
    }
    a0 = fmaxf(a0, 0.0f);
    a1 = fmaxf(a1, 0.0f);
    float part = a0 * r1W[lane] + a1 * r1W[64 + lane];
#pragma unroll
    for (int off = 32; off > 0; off >>= 1) part += __shfl_down(part, off);
    if (lane == 0) out[g] = part + r1b[0];
}

// ---------------- fast path: deterministic pooling (batch is SORTED) ----------------

__global__ __launch_bounds__(256) void gptr_kernel(
    const int* __restrict__ batch, int* __restrict__ gptr) {
    int n = blockIdx.x * 256 + threadIdx.x;
    if (n >= N_NODES) return;
    int b = batch[n];
    int bp = (n == 0) ? -1 : batch[n - 1];
    for (int g = bp + 1; g <= b; g++) gptr[g] = n;
    if (n == N_NODES - 1)
        for (int g = b + 1; g <= N_GRAPHS; g++) gptr[g] = N_NODES;
}

__global__ __launch_bounds__(256) void pool_seg_kernel(
    const float* __restrict__ h, const int* __restrict__ gptr,
    float* __restrict__ pool) {
    int tid = threadIdx.x, w = tid >> 6, lane = tid & 63;
    int g = blockIdx.x * 4 + w;
    if (g >= N_GRAPHS) return;
    int rs = gptr[g], re = gptr[g + 1];
    float acc = 0.0f;
    for (int n = rs; n < re; n++) acc += h[(size_t)n * ND + lane];
    pool[(size_t)g * ND + lane] = acc;
}

__global__ __launch_bounds__(256) void readout2_kernel(
    const float* __restrict__ pool, const int* __restrict__ gptr,
    const float* __restrict__ r0W, const float* __restrict__ r0b,
    const float* __restrict__ r1W, const float* __restrict__ r1b,
    float* __restrict__ out) {
    __shared__ float w0s[64 * 128];
    __shared__ float pb[4][64];
    int tid = threadIdx.x;
    for (int idx = tid; idx < 64 * 128; idx += 256) {
        int k = idx >> 7, j = idx & 127;
        w0s[((k >> 2) * 128 + j) * 4 + (k & 3)] = r0W[idx];
    }
    __syncthreads();
    int w = tid >> 6, lane = tid & 63;
    int g = blockIdx.x * 4 + w;
    float c = fmaxf((float)(gptr[g + 1] - gptr[g]), 1.0f);
    float pv = pool[(size_t)g * ND + lane] / c;
    pb[w][lane] = pv;
    __syncthreads();

    float a0 = r0b[lane], a1 = r0b[64 + lane];
#pragma unroll
    for (int k4 = 0; k4 < 16; k4++) {
        float4 v = *reinterpret_cast<const float4*>(&pb[w][k4 * 4]);
        float4 qa = *reinterpret_cast<const float4*>(&w0s[(k4 * 128 + lane) * 4]);
        float4 qb = *reinterpret_cast<const float4*>(&w0s[(k4 * 128 + 64 + lane) * 4]);
        a0 = fmaf(v.x, qa.x, a0); a0 = fmaf(v.y, qa.y, a0);
        a0 = fmaf(v.z, qa.z, a0); a0 = fmaf(v.w, qa.w, a0);
        a1 = fmaf(v.x, qb.x, a1); a1 = fmaf(v.y, qb.y, a1);
        a1 = fmaf(v.z, qb.z, a1); a1 = fmaf(v.w, qb.w, a1);
    }
    a0 = fmaxf(a0, 0.0f);
    a1 = fmaxf(a1, 0.0f);
    float part = a0 * r1W[lane] + a1 * r1W[64 + lane];
#pragma unroll
    for (int off = 32; off > 0; off >>= 1) part += __shfl_down(part, off);
    if (lane == 0) out[g] = part + r1b[0];
}

// ---------------- old (fallback) msg path ----------------

__global__ __launch_bounds__(256) void wfrag_setup_kernel(
    const float* __restrict__ m0W, const float* __restrict__ m0b,
    const float* __restrict__ m1W,
    const float* __restrict__ eeW, const float* __restrict__ eeB,
    unsigned int* __restrict__ wf, float* __restrict__ b0p) {
    int l = blockIdx.x;
    int tid = threadIdx.x;
    const float* W0 = m0W + (size_t)l * 144 * 64;
    const float* W1 = m1W + (size_t)l * 64 * 64;
    unsigned int* base = wf + (size_t)l * WF_STRIDE;

    if (tid < 64) {
        float acc = m0b[l * 64 + tid];
#pragma unroll
        for (int kp = 0; kp < 16; kp++)
            acc = fmaf(eeB[kp], W0[(128 + kp) * 64 + tid], acc);
        b0p[l * 64 + tid] = acc;
    }

    for (int u = tid; u < 28 * 64; u += 256) {
        int slot = u >> 6, lane = u & 63;
        int g = lane >> 4, c16 = lane & 15;
        float w8[8];
        unsigned int* dsthi;
        unsigned int* dstlo;
        if (slot < 20) {
            int t = slot >> 2, n = slot & 3;
#pragma unroll
            for (int j = 0; j < 8; j++) {
                int k = 32 * t + 8 * g + j;
                float wv = 0.0f;
                if (t < 4) {
                    wv = W0[k * 64 + 16 * n + c16];
                } else if (g == 0 && j < 4) {
                    float a = 0.0f;
                    for (int kp = 0; kp < 16; kp++)
                        a = fmaf(eeW[j * 16 + kp], W0[(128 + kp) * 64 + 16 * n + c16], a);
                    wv = a;
                }
                w8[j] = wv;
            }
            dsthi = base + ((size_t)slot * 64 + lane) * 4;
            dstlo = base + 5120 + ((size_t)slot * 64 + lane) * 4;
        } else {
            int s2 = slot - 20;
#pragma unroll
            for (int j = 0; j < 8; j++) {
                int k = 32 * (s2 >> 2) + 8 * g + j;
                w8[j] = W1[k * 64 + 16 * (s2 & 3) + c16];
            }
            dsthi = base + 10240 + ((size_t)s2 * 64 + lane) * 4;
            dstlo = base + 12288 + ((size_t)s2 * 64 + lane) * 4;
        }
        unsigned int hi[4], lo[4];
        split8(w8, hi, lo);
#pragma unroll
        for (int i = 0; i < 4; i++) { dsthi[i] = hi[i]; dstlo[i] = lo[i]; }
    }
}

#define MSG_BLOCKS 1250
#define MSG_SLOTS (MSG_BLOCKS * 4)
#define MSG_ITERS 5
__global__ __launch_bounds__(256) void msg_mfma_kernel(
    const float* __restrict__ h, const int* __restrict__ ei, const int* __restrict__ ea,
    const unsigned int* __restrict__ wf, const float* __restrict__ b0p,
    const float* __restrict__ b1, float* __restrict__ agg) {
    __shared__ unsigned int mid[4][2048];
    const unsigned int* w0h = wf;
    const unsigned int* w0l = wf + 5120;
    const unsigned int* w1h = wf + 10240;
    const unsigned int* w1l = wf + 12288;
    int tid = threadIdx.x, w = tid >> 6, l = tid & 63, g = l >> 4, col = l & 15;
    unsigned int* midw = mid[w];

    float bias0v[4], bias1v[4];
#pragma unroll
    for (int n = 0; n < 4; n++) { bias0v[n] = b0p[16 * n + col]; bias1v[n] = b1[16 * n + col]; }

    int slot = blockIdx.x * 4 + w;
    for (int it = 0; it < MSG_ITERS; ++it) {
        int tb = (it * MSG_SLOTS + slot) * 32;
        int e0 = tb + col, e1 = e0 + 16;
        int s0 = ei[e0], s1 = ei[e1], d0 = ei[N_EDGES + e0], d1 = ei[N_EDGES + e1];
        int dr[2][4];
#pragma unroll
        for (int m = 0; m < 2; m++)
#pragma unroll
            for (int ri = 0; ri < 4; ri++)
                dr[m][ri] = ei[N_EDGES + tb + 16 * m + 4 * g + ri];

        unsigned int ah[4][2][4], alo[4][2][4];
        const float* ps[2] = { h + (size_t)s0 * 64, h + (size_t)s1 * 64 };
        const float* pd[2] = { h + (size_t)d0 * 64, h + (size_t)d1 * 64 };
#pragma unroll
        for (int t = 0; t < 4; t++) {
#pragma unroll
            for (int m = 0; m < 2; m++) {
                const float* p = (t < 2 ? ps[m] : pd[m]) + (t & 1) * 32 + 8 * g;
                f32x4 v0 = *reinterpret_cast<const f32x4*>(p);
                f32x4 v1 = *reinterpret_cast<const f32x4*>(p + 4);
                float v[8];
#pragma unroll
                for (int i = 0; i < 4; i++) { v[i] = v0[i]; v[4 + i] = v1[i]; }
                split8(v, ah[t][m], alo[t][m]);
            }
        }
        unsigned int a4[2][2];
        {
            int4 q0 = *reinterpret_cast<const int4*>(&ea[(size_t)e0 * 4]);
            int4 q1 = *reinterpret_cast<const int4*>(&ea[(size_t)e1 * 4]);
            a4[0][0] = g == 0 ? ((unsigned int)f2bf((float)q0.x) | ((unsigned int)f2bf((float)q0.y) << 16)) : 0u;
            a4[0][1] = g == 0 ? ((unsigned int)f2bf((float)q0.z) | ((unsigned int)f2bf((float)q0.w) << 16)) : 0u;
            a4[1][0] = g == 0 ? ((unsigned int)f2bf((float)q1.x) | ((unsigned int)f2bf((float)q1.y) << 16)) : 0u;
            a4[1][1] = g == 0 ? ((unsigned int)f2bf((float)q1.z) | ((unsigned int)f2bf((float)q1.w) << 16)) : 0u;
        }

        f32x4 acc[2][4];
#pragma unroll
        for (int m = 0; m < 2; m++)
#pragma unroll
            for (int n = 0; n < 4; n++) acc[m][n] = (f32x4)0.0f;
#pragma unroll
        for (int t = 0; t < 5; t++) {
#pragma unroll
            for (int n = 0; n < 4; n++) {
                uint4 bh = *reinterpret_cast<const uint4*>(&w0h[((size_t)(t * 4 + n) * 64 + l) * 4]);
                uint4 bl = *reinterpret_cast<const uint4*>(&w0l[((size_t)(t * 4 + n) * 64 + l) * 4]);
                short8 Bh = mk4(bh.x, bh.y, bh.z, bh.w);
                short8 Bl = mk4(bl.x, bl.y, bl.z, bl.w);
#pragma unroll
                for (int m = 0; m < 2; m++) {
                    short8 Ah, Al;
                    if (t < 4) {
                        Ah = mk4(ah[t][m][0], ah[t][m][1], ah[t][m][2], ah[t][m][3]);
                        Al = mk4(alo[t][m][0], alo[t][m][1], alo[t][m][2], alo[t][m][3]);
                    } else {
                        Ah = mk4(a4[m][0], a4[m][1], 0u, 0u);
                        Al = mk4(0u, 0u, 0u, 0u);
                    }
                    acc[m][n] = __builtin_amdgcn_mfma_f32_16x16x32_bf16(Ah, Bh, acc[m][n], 0, 0, 0);
                    acc[m][n] = __builtin_amdgcn_mfma_f32_16x16x32_bf16(Ah, Bl, acc[m][n], 0, 0, 0);
                    if (t < 4)
                        acc[m][n] = __builtin_amdgcn_mfma_f32_16x16x32_bf16(Al, Bh, acc[m][n], 0, 0, 0);
                }
            }
        }

#pragma unroll
        for (int m = 0; m < 2; m++)
#pragma unroll
            for (int n = 0; n < 4; n++)
#pragma unroll
                for (int ri = 0; ri < 4; ri++) {
                    float v = fmaxf(acc[m][n][ri] + bias0v[n], 0.0f);
                    unsigned short hh = f2bf(v);
                    unsigned short ll = f2bf(v - bf2f(hh));
                    int r = 16 * m + 4 * g + ri, c = 16 * n + col;
                    midw[r * 64 + (c ^ ((r & 7) << 2))] = (unsigned int)hh | ((unsigned int)ll << 16);
                }

        unsigned int a2h[2][2][4], a2l[2][2][4];
#pragma unroll
        for (int m = 0; m < 2; m++) {
            int r = col + 16 * m;
            int swz = (r & 7) << 2;
#pragma unroll
            for (int t2 = 0; t2 < 2; t2++) {
                int bc = 32 * t2 + 8 * g;
                uint4 q0 = *reinterpret_cast<const uint4*>(&midw[r * 64 + (bc ^ swz)]);
                uint4 q1 = *reinterpret_cast<const uint4*>(&midw[r * 64 + ((bc + 4) ^ swz)]);
                a2h[m][t2][0] = (q0.x & 0xFFFFu) | (q0.y << 16);
                a2l[m][t2][0] = (q0.x >> 16) | (q0.y & 0xFFFF0000u);
                a2h[m][t2][1] = (q0.z & 0xFFFFu) | (q0.w << 16);
                a2l[m][t2][1] = (q0.z >> 16) | (q0.w & 0xFFFF0000u);
                a2h[m][t2][2] = (q1.x & 0xFFFFu) | (q1.y << 16);
                a2l[m][t2][2] = (q1.x >> 16) | (q1.y & 0xFFFF0000u);
                a2h[m][t2][3] = (q1.z & 0xFFFFu) | (q1.w << 16);
                a2l[m][t2][3] = (q1.z >> 16) | (q1.w & 0xFFFF0000u);
            }
        }

        f32x4 acc2[2][4];
#pragma unroll
        for (int m = 0; m < 2; m++)
#pragma unroll
            for (int n = 0; n < 4; n++) acc2[m][n] = (f32x4)0.0f;
#pragma unroll
        for (int t2 = 0; t2 < 2; t2++) {
#pragma unroll
            for (int n = 0; n < 4; n++) {
                uint4 bh = *reinterpret_cast<const uint4*>(&w1h[((size_t)(t2 * 4 + n) * 64 + l) * 4]);
                uint4 bl = *reinterpret_cast<const uint4*>(&w1l[((size_t)(t2 * 4 + n) * 64 + l) * 4]);
                short8 Bh = mk4(bh.x, bh.y, bh.z, bh.w);
                short8 Bl = mk4(bl.x, bl.y, bl.z, bl.w);
#pragma unroll
                for (int m = 0; m < 2; m++) {
                    short8 Ah = mk4(a2h[m][t2][0], a2h[m][t2][1], a2h[m][t2][2], a2h[m][t2][3]);
                    short8 Al = mk4(a2l[m][t2][0], a2l[m][t2][1], a2l[m][t2][2], a2l[m][t2][3]);
                    acc2[m][n] = __builtin_amdgcn_mfma_f32_16x16x32_bf16(Ah, Bh, acc2[m][n], 0, 0, 0);
                    acc2[m][n] = __builtin_amdgcn_mfma_f32_16x16x32_bf16(Ah, Bl, acc2[m][n], 0, 0, 0);
                    acc2[m][n] = __builtin_amdgcn_mfma_f32_16x16x32_bf16(Al, Bh, acc2[m][n], 0, 0, 0);
                }
            }
        }

#pragma unroll
        for (int m = 0; m < 2; m++)
#pragma unroll
            for (int n = 0; n < 4; n++)
#pragma unroll
                for (int ri = 0; ri < 4; ri++) {
                    float v = acc2[m][n][ri] + bias1v[n];
                    ATOMIC_ADD_F32(&agg[(size_t)dr[m][ri] * 64 + 16 * n + col], v);
                }
    }
}

// ---------------- fast path: CSR build (deterministic) ----------------

__global__ __launch_bounds__(256) void hist_kernel(
    const int* __restrict__ ei, int* __restrict__ deg) {
    int e = blockIdx.x * 256 + threadIdx.x;
    if (e < N_EDGES) atomicAdd(&deg[ei[N_EDGES + e]], 1);
}

#define NCHUNK 196
__global__ __launch_bounds__(256) void scan1_kernel(
    const int* __restrict__ deg, int* __restrict__ rowptr, int* __restrict__ chunksum) {
    __shared__ int sb[256];
    int b = blockIdx.x, t = threadIdx.x, idx = b * 256 + t;
    int v = (idx < N_NODES) ? deg[idx] : 0;
    sb[t] = v;
    __syncthreads();
    for (int off = 1; off < 256; off <<= 1) {
        int x = (t >= off) ? sb[t - off] : 0;
        __syncthreads();
        sb[t] += x;
        __syncthreads();
    }
    if (idx < N_NODES) rowptr[idx] = sb[t] - v;
    if (t == 255) chunksum[b] = sb[255];
}

__global__ __launch_bounds__(256) void scan2_kernel(int* __restrict__ chunksum) {
    __shared__ int sb[256];
    int t = threadIdx.x;
    int v = (t < NCHUNK) ? chunksum[t] : 0;
    sb[t] = v;
    __syncthreads();
    for (int off = 1; off < 256; off <<= 1) {
        int x = (t >= off) ? sb[t - off] : 0;
        __syncthreads();
        sb[t] += x;
        __syncthreads();
    }
    if (t < NCHUNK) chunksum[t] = sb[t] - v;
}

__global__ __launch_bounds__(256) void scan3_kernel(
    int* __restrict__ rowptr, const int* __restrict__ chunksum, int* __restrict__ cursor) {
    int b = blockIdx.x, t = threadIdx.x, idx = b * 256 + t;
    if (idx < N_NODES) {
        int r = rowptr[idx] + chunksum[b];
        rowptr[idx] = r;
        cursor[idx] = r;
    }
    if (idx == 0) rowptr[N_NODES] = N_EDGES;
}

__global__ __launch_bounds__(256) void scatter_kernel(
    const int* __restrict__ ei, int* __restrict__ cursor, int* __restrict__ eids) {
    int e = blockIdx.x * 256 + threadIdx.x;
    if (e >= N_EDGES) return;
    int d = ei[N_EDGES + e];
    int p = atomicAdd(&cursor[d], 1);
    eids[p] = e;
}

// Wave-per-node bitonic sort (64 lanes) by edge id + parallel gather.
// Writes packed (attr_idx << 16) | src  (src < 65536, idx < 81).
__global__ __launch_bounds__(256) void sortseg_kernel(
    const int* __restrict__ rowptr, int* __restrict__ eids,
    const int* __restrict__ ei, const int* __restrict__ ea,
    unsigned int* __restrict__ spk) {
    int tid = threadIdx.x, lane = tid & 63;
    int n = blockIdx.x * 4 + (tid >> 6);
    if (n >= N_NODES) return;
    int rs = rowptr[n], re = rowptr[n + 1];
    int len = re - rs;
    if (len <= 0) return;

    if (len <= 64) {
        int key = (lane < len) ? eids[rs + lane] : 0x7FFFFFFF;
#pragma unroll
        for (int k = 2; k <= 64; k <<= 1) {
#pragma unroll
            for (int j = k >> 1; j > 0; j >>= 1) {
                int other = __shfl_xor(key, j);
                bool up = ((lane & k) == 0);
                bool lower = ((lane & j) == 0);
                key = ((lower == up) ? min(key, other) : max(key, other));
            }
        }
        if (lane < len) {
            int e = key;
            int4 q = *reinterpret_cast<const int4*>(&ea[(size_t)e * 4]);
            unsigned int idx = (unsigned int)(q.x + 3 * q.y + 9 * q.z + 27 * q.w);
            spk[rs + lane] = (unsigned int)ei[e] | (idx << 16);
        }
    } else {
        if (lane == 0) {
            for (int i = rs + 1; i < re; i++) {
                int k2 = eids[i];
                int j = i - 1;
                while (j >= rs && eids[j] > k2) { eids[j + 1] = eids[j]; j--; }
                eids[j + 1] = k2;
            }
        }
        __builtin_amdgcn_wave_barrier();
        for (int p = rs + lane; p < re; p += 64) {
            int e = eids[p];
            int4 q = *reinterpret_cast<const int4*>(&ea[(size_t)e * 4]);
            unsigned int idx = (unsigned int)(q.x + 3 * q.y + 9 * q.z + 27 * q.w);
            spk[p] = (unsigned int)ei[e] | (idx << 16);
        }
    }
}

// ---------------- fast path: weight prep ----------------

__global__ __launch_bounds__(256) void wsetup2_kernel(
    const float* __restrict__ m0W, const float* __restrict__ m0b,
    const float* __restrict__ m1W,
    const float* __restrict__ eeW, const float* __restrict__ eeB,
    unsigned int* __restrict__ wf2, float* __restrict__ Cbuf, float* __restrict__ b0p) {
    int l = blockIdx.x;
    int tid = threadIdx.x;
    const float* W0 = m0W + (size_t)l * 144 * 64;
    const float* W1 = m1W + (size_t)l * 64 * 64;
    unsigned int* base = wf2 + (size_t)l * WF2_STRIDE;

    if (tid < 64) {
        float acc = m0b[l * 64 + tid];
#pragma unroll
        for (int kp = 0; kp < 16; kp++)
            acc = fmaf(eeB[kp], W0[(128 + kp) * 64 + tid], acc);
        b0p[l * 64 + tid] = acc;
    }
    {
        int k = tid >> 6, f = tid & 63;
        float a = 0.0f;
#pragma unroll
        for (int kp = 0; kp < 16; kp++)
            a = fmaf(eeW[k * 16 + kp], W0[(128 + kp) * 64 + f], a);
        Cbuf[l * 256 + tid] = a;
    }
    for (int u = tid; u < 16 * 64; u += 256) {
        int slot = u >> 6, lane = u & 63;
        int g = lane >> 4, c16 = lane & 15;
        int t = slot >> 3, n = slot & 7;
        float w8[8];
#pragma unroll
        for (int j = 0; j < 8; j++) {
            int k = 32 * t + 8 * g + j;
            int col = 16 * n + c16;
            w8[j] = (col < 64) ? W0[k * 64 + col] : W0[(64 + k) * 64 + (col - 64)];
        }
        unsigned int hi[4], lo[4];
        split8(w8, hi, lo);
#pragma unroll
        for (int i = 0; i < 4; i++) {
            base[((size_t)slot * 64 + lane) * 4 + i] = hi[i];
            base[4096 + ((size_t)slot * 64 + lane) * 4 + i] = lo[i];
        }
    }
    for (int u = tid; u < 8 * 64; u += 256) {
        int slot = u >> 6, lane = u & 63;
        int g = lane >> 4, c16 = lane & 15;
        int t2 = slot >> 2, n2 = slot & 3;
        float w8[8];
#pragma unroll
        for (int j = 0; j < 8; j++)
            w8[j] = W1[(32 * t2 + 8 * g + j) * 64 + 16 * n2 + c16];
        unsigned int hi[4], lo[4];
        split8(w8, hi, lo);
#pragma unroll
        for (int i = 0; i < 4; i++) {
            base[8192 + ((size_t)slot * 64 + lane) * 4 + i] = hi[i];
            base[10240 + ((size_t)slot * 64 + lane) * 4 + i] = lo[i];
        }
    }
}

// LUT[l][idx][f] = sum_k digit_k(idx) * C[l][k][f], idx in [0,81)
__global__ __launch_bounds__(256) void lut_kernel(
    const float* __restrict__ Cbuf, float* __restrict__ LUT) {
    int id = blockIdx.x * 256 + threadIdx.x;
    if (id >= 3 * LUTN) return;
    int f = id & 63;
    int rest = id >> 6;
    int idx = rest % 81;
    int l = rest / 81;
    const float* C = Cbuf + l * 256;
    int i0 = idx % 3, i1 = (idx / 3) % 3, i2 = (idx / 9) % 3, i3 = idx / 27;
    float v = (float)i0 * C[f];
    v = fmaf((float)i1, C[64 + f], v);
    v = fmaf((float)i2, C[128 + f], v);
    v = fmaf((float)i3, C[192 + f], v);
    LUT[id] = v;
}

// P[l] = [W1; b1] @ Wih  (65 x 192 per layer), fully parallel.
#define PMAT_BLOCKS ((PN + 255) / 256)
__global__ __launch_bounds__(256) void pmat_kernel(
    const float* __restrict__ gWih, const float* __restrict__ m1W,
    const float* __restrict__ m1b, float* __restrict__ P) {
    int l = blockIdx.y;
    int idx = blockIdx.x * 256 + threadIdx.x;
    if (idx >= PN) return;
    int r = idx / 192, c = idx - r * 192;
    const float* Wih = gWih + (size_t)l * 64 * 192;
    const float* row = (r < 64) ? (m1W + (size_t)l * 64 * 64 + (size_t)r * 64)
                                : (m1b + (size_t)l * 64);
    float a = 0.0f;
    for (int q = 0; q < 64; q++) a = fmaf(row[q], Wih[q * 192 + c], a);
    P[(size_t)l * PN + idx] = a;
}

// GRU weight fragments with W1 folded; reads precomputed P.
__global__ __launch_bounds__(256) void wsetup3_kernel(
    const float* __restrict__ gbih, const float* __restrict__ gWhh,
    const float* __restrict__ gbhh, const float* __restrict__ P,
    unsigned int* __restrict__ wf3, float* __restrict__ bb) {
    int l = blockIdx.x;
    int tid = threadIdx.x;
    const float* Whh = gWhh + (size_t)l * 64 * 192;
    const float* bih = gbih + (size_t)l * 192;
    const float* bhh = gbhh + (size_t)l * 192;
    const float* Pl = P + (size_t)l * PN;
    unsigned int* base = wf3 + (size_t)l * GRU_STRIDE;

    for (int f = tid; f < 448; f += 256) {
        float v;
        if (f < 128) v = bih[f] + bhh[f];
        else if (f < 192) v = bih[f];
        else if (f < 256) v = bhh[f - 64];
        else if (f < 384) v = Pl[64 * 192 + (f - 256)];
        else v = Pl[64 * 192 + 128 + (f - 384)];
        bb[l * 512 + f] = v;
    }

    for (int u = tid; u < 48 * 64; u += 256) {
        int slot = u >> 6, lane = u & 63;
        int g = lane >> 4, c16 = lane & 15;
        float w8[8];
        unsigned int *dsthi, *dstlo;
        if (slot < 32) {
            int t = slot >> 3, n = slot & 7;
            int c = 16 * n + c16;
#pragma unroll
            for (int j = 0; j < 8; j++) {
                if (t < 2) {
                    int k = 32 * t + 8 * g + j;
                    w8[j] = Pl[k * 192 + c];
                } else {
                    int k = 32 * (t - 2) + 8 * g + j;
                    w8[j] = Whh[k * 192 + c];
                }
            }
            dsthi = base + ((size_t)slot * 64 + lane) * 4;
            dstlo = base + 8192 + ((size_t)slot * 64 + lane) * 4;
        } else if (slot < 40) {
            int s = slot - 32;
            int t = s >> 2, n = s & 3;
            int c = 128 + 16 * n + c16;
#pragma unroll
            for (int j = 0; j < 8; j++)
                w8[j] = Pl[(32 * t + 8 * g + j) * 192 + c];
            dsthi = base + 16384 + ((size_t)s * 64 + lane) * 4;
            dstlo = base + 18432 + ((size_t)s * 64 + lane) * 4;
        } else {
            int s = slot - 40;
            int t = s >> 2, n = s & 3;
            int c = 128 + 16 * n + c16;
#pragma unroll
            for (int j = 0; j < 8; j++)
                w8[j] = Whh[(32 * t + 8 * g + j) * 192 + c];
            dsthi = base + 20480 + ((size_t)s * 64 + lane) * 4;
            dstlo = base + 22528 + ((size_t)s * 64 + lane) * 4;
        }
        unsigned int hi[4], lo[4];
        split8(w8, hi, lo);
#pragma unroll
        for (int i = 0; i < 4; i++) { dsthi[i] = hi[i]; dstlo[i] = lo[i]; }
    }
}

// ---------------- fast path: per-layer kernels ----------------

#define PH_TILES ((N_NODES + 31) / 32)
__global__ __launch_bounds__(256) void ph_kernel(
    const float* __restrict__ h, const unsigned int* __restrict__ wf2,
    const float* __restrict__ b0p, float* __restrict__ Pa, float* __restrict__ Pb) {
    int tid = threadIdx.x, w = tid >> 6, l = tid & 63, g = l >> 4, c16 = l & 15;
    int tile = blockIdx.x * 4 + w;
    if (tile >= PH_TILES) return;
    int base = tile * 32;

    unsigned int ah[2][2][4], al_[2][2][4];
#pragma unroll
    for (int m = 0; m < 2; m++) {
        int row = base + 16 * m + c16;
        if (row >= N_NODES) row = N_NODES - 1;
#pragma unroll
        for (int t = 0; t < 2; t++) {
            const float* p = h + (size_t)row * 64 + 32 * t + 8 * g;
            f32x4 v0 = *reinterpret_cast<const f32x4*>(p);
            f32x4 v1 = *reinterpret_cast<const f32x4*>(p + 4);
            float v[8];
#pragma unroll
            for (int i = 0; i < 4; i++) { v[i] = v0[i]; v[4 + i] = v1[i]; }
            split8(v, ah[m][t], al_[m][t]);
        }
    }

    f32x4 acc[2][8];
#pragma unroll
    for (int m = 0; m < 2; m++)
#pragma unroll
        for (int n = 0; n < 8; n++) acc[m][n] = (f32x4)0.0f;

    const unsigned int* wh = wf2;
    const unsigned int* wl = wf2 + 4096;
#pragma unroll
    for (int t = 0; t < 2; t++) {
#pragma unroll
        for (int n = 0; n < 8; n++) {
            int slot = t * 8 + n;
            uint4 bh = *reinterpret_cast<const uint4*>(&wh[((size_t)slot * 64 + l) * 4]);
            uint4 bl = *reinterpret_cast<const uint4*>(&wl[((size_t)slot * 64 + l) * 4]);
            short8 Bh = mk4(bh.x, bh.y, bh.z, bh.w);
            short8 Bl = mk4(bl.x, bl.y, bl.z, bl.w);
#pragma unroll
            for (int m = 0; m < 2; m++) {
                short8 Ah = mk4(ah[m][t][0], ah[m][t][1], ah[m][t][2], ah[m][t][3]);
                short8 Al = mk4(al_[m][t][0], al_[m][t][1], al_[m][t][2], al_[m][t][3]);
                acc[m][n] = __builtin_amdgcn_mfma_f32_16x16x32_bf16(Ah, Bh, acc[m][n], 0, 0, 0);
                acc[m][n] = __builtin_amdgcn_mfma_f32_16x16x32_bf16(Ah, Bl, acc[m][n], 0, 0, 0);
                acc[m][n] = __builtin_amdgcn_mfma_f32_16x16x32_bf16(Al, Bh, acc[m][n], 0, 0, 0);
            }
        }
    }

#pragma unroll
    for (int m = 0; m < 2; m++)
#pragma unroll
        for (int n = 0; n < 8; n++)
#pragma unroll
            for (int ri = 0; ri < 4; ri++) {
                int row = base + 16 * m + 4 * g + ri;
                if (row < N_NODES) {
                    if (n < 4)
                        Pa[(size_t)row * 64 + 16 * n + c16] = acc[m][n][ri];
                    else
                        Pb[(size_t)row * 64 + 16 * (n - 4) + c16] =
                            acc[m][n][ri] + b0p[16 * (n - 4) + c16];
                }
            }
}

// Edge aggregation: packed (idx<<16|src) + LUT; 16-deep batched gathers.
// Accumulation order ascending -> bitwise-identical output. (Round-13 optimum.)
#define AGG_BLOCKS 2048
__global__ __launch_bounds__(256) void agg_edge_kernel(
    const float* __restrict__ Pa, const float* __restrict__ Pb,
    const unsigned int* __restrict__ spk, const int* __restrict__ rowptr,
    const float* __restrict__ LUT, float* __restrict__ aggmid) {
    int tid = threadIdx.x;
    int lane = tid & 63;
    int wid = blockIdx.x * 4 + (tid >> 6);
    const int nw = AGG_BLOCKS * 4;

    for (int n = wid; n < N_NODES; n += nw) {
        int rs = rowptr[n], re = rowptr[n + 1];
        float pbv = Pb[(size_t)n * 64 + lane];
        float acc = 0.0f;
        int p = rs;
        for (; p + 16 <= re; p += 16) {
            unsigned int u[16];
#pragma unroll
            for (int i = 0; i < 16; i++) u[i] = spk[p + i];
            float pav[16], lv[16];
#pragma unroll
            for (int i = 0; i < 16; i++) pav[i] = Pa[(size_t)(u[i] & 0xFFFFu) * 64 + lane];
#pragma unroll
            for (int i = 0; i < 16; i++) lv[i] = LUT[(size_t)(u[i] >> 16) * 64 + lane];
#pragma unroll
            for (int i = 0; i < 16; i++)
                acc += fmaxf(pav[i] + pbv + lv[i], 0.0f);
        }
        for (; p + 8 <= re; p += 8) {
            unsigned int u[8];
#pragma unroll
            for (int i = 0; i < 8; i++) u[i] = spk[p + i];
            float pav[8], lv[8];
#pragma unroll
            for (int i = 0; i < 8; i++) pav[i] = Pa[(size_t)(u[i] & 0xFFFFu) * 64 + lane];
#pragma unroll
            for (int i = 0; i < 8; i++) lv[i] = LUT[(size_t)(u[i] >> 16) * 64 + lane];
#pragma unroll
            for (int i = 0; i < 8; i++)
                acc += fmaxf(pav[i] + pbv + lv[i], 0.0f);
        }
        for (; p < re; ++p) {
            unsigned int u = spk[p];
            float v = Pa[(size_t)(u & 0xFFFFu) * 64 + lane] + pbv +
                      LUT[(size_t)(u >> 16) * 64 + lane];
            acc += fmaxf(v, 0.0f);
        }
        aggmid[(size_t)n * 64 + lane] = acc;
    }
}

// MFMA GRU with W1 folded: A t=0,1 = aggmid, t=2,3 = h. deg-scaled bias in epilogue.
__global__ __launch_bounds__(256) void gru_mfma2_kernel(
    float* __restrict__ h, const float* __restrict__ aggmid,
    const int* __restrict__ deg,
    const unsigned int* __restrict__ wf3, const float* __restrict__ bb) {
    int tid = threadIdx.x, w = tid >> 6, l = tid & 63, g = l >> 4, c16 = l & 15;
    int tile = blockIdx.x * 4 + w;
    if (tile >= PH_TILES) return;
    int base = tile * 32;

    unsigned int aAh[2][2][4], aAl[2][2][4];
    unsigned int hAh[2][2][4], hAl[2][2][4];
#pragma unroll
    for (int m = 0; m < 2; m++) {
        int row = base + 16 * m + c16;
        if (row >= N_NODES) row = N_NODES - 1;
#pragma unroll
        for (int t = 0; t < 2; t++) {
            const float* pa = aggmid + (size_t)row * 64 + 32 * t + 8 * g;
            const float* ph = h + (size_t)row * 64 + 32 * t + 8 * g;
            f32x4 va0 = *reinterpret_cast<const f32x4*>(pa);
            f32x4 va1 = *reinterpret_cast<const f32x4*>(pa + 4);
            f32x4 vh0 = *reinterpret_cast<const f32x4*>(ph);
            f32x4 vh1 = *reinterpret_cast<const f32x4*>(ph + 4);
            float v[8];
#pragma unroll
            for (int i = 0; i < 4; i++) { v[i] = va0[i]; v[4 + i] = va1[i]; }
            split8(v, aAh[m][t], aAl[m][t]);
#pragma unroll
            for (int i = 0; i < 4; i++) { v[i] = vh0[i]; v[4 + i] = vh1[i]; }
            split8(v, hAh[m][t], hAl[m][t]);
        }
    }

    f32x4 accS[2][8];
#pragma unroll
    for (int m = 0; m < 2; m++)
#pragma unroll
        for (int n = 0; n < 8; n++) accS[m][n] = (f32x4)0.0f;
#pragma unroll
    for (int t = 0; t < 4; t++) {
#pragma unroll
        for (int n = 0; n < 8; n++) {
            int slot = t * 8 + n;
            uint4 bh = *reinterpret_cast<const uint4*>(&wf3[((size_t)slot * 64 + l) * 4]);
            uint4 bl = *reinterpret_cast<const uint4*>(&wf3[8192 + ((size_t)slot * 64 + l) * 4]);
            short8 Bh = mk4(bh.x, bh.y, bh.z, bh.w);
            short8 Bl = mk4(bl.x, bl.y, bl.z, bl.w);
#pragma unroll
            for (int m = 0; m < 2; m++) {
                const unsigned int* uh = (t < 2) ? aAh[m][t] : hAh[m][t - 2];
                const unsigned int* ul = (t < 2) ? aAl[m][t] : hAl[m][t - 2];
                short8 Ah = mk4(uh[0], uh[1], uh[2], uh[3]);
                short8 Al = mk4(ul[0], ul[1], ul[2], ul[3]);
                accS[m][n] = __builtin_amdgcn_mfma_f32_16x16x32_bf16(Ah, Bh, accS[m][n], 0, 0, 0);
                accS[m][n] = __builtin_amdgcn_mfma_f32_16x16x32_bf16(Ah, Bl, accS[m][n], 0, 0, 0);
                accS[m][n] = __builtin_amdgcn_mfma_f32_16x16x32_bf16(Al, Bh, accS[m][n], 0, 0, 0);
            }
        }
    }

    f32x4 accI[2][4], accH[2][4];
#pragma unroll
    for (int m = 0; m < 2; m++)
#pragma unroll
        for (int n = 0; n < 4; n++) { accI[m][n] = (f32x4)0.0f; accH[m][n] = (f32x4)0.0f; }
#pragma unroll
    for (int t = 0; t < 2; t++) {
#pragma unroll
        for (int n = 0; n < 4; n++) {
            int s = t * 4 + n;
            uint4 bhi = *reinterpret_cast<const uint4*>(&wf3[16384 + ((size_t)s * 64 + l) * 4]);
            uint4 bli = *reinterpret_cast<const uint4*>(&wf3[18432 + ((size_t)s * 64 + l) * 4]);
            uint4 bhh = *reinterpret_cast<const uint4*>(&wf3[20480 + ((size_t)s * 64 + l) * 4]);
            uint4 blh = *reinterpret_cast<const uint4*>(&wf3[22528 + ((size_t)s * 64 + l) * 4]);
            short8 BhI = mk4(bhi.x, bhi.y, bhi.z, bhi.w);
            short8 BlI = mk4(bli.x, bli.y, bli.z, bli.w);
            short8 BhH = mk4(bhh.x, bhh.y, bhh.z, bhh.w);
            short8 BlH = mk4(blh.x, blh.y, blh.z, blh.w);
#pragma unroll
            for (int m = 0; m < 2; m++) {
                short8 Ah = mk4(aAh[m][t][0], aAh[m][t][1], aAh[m][t][2], aAh[m][t][3]);
                short8 Al = mk4(aAl[m][t][0], aAl[m][t][1], aAl[m][t][2], aAl[m][t][3]);
                accI[m][n] = __builtin_amdgcn_mfma_f32_16x16x32_bf16(Ah, BhI, accI[m][n], 0, 0, 0);
                accI[m][n] = __builtin_amdgcn_mfma_f32_16x16x32_bf16(Ah, BlI, accI[m][n], 0, 0, 0);
                accI[m][n] = __builtin_amdgcn_mfma_f32_16x16x32_bf16(Al, BhI, accI[m][n], 0, 0, 0);
                short8 Hh = mk4(hAh[m][t][0], hAh[m][t][1], hAh[m][t][2], hAh[m][t][3]);
                short8 Hl = mk4(hAl[m][t][0], hAl[m][t][1], hAl[m][t][2], hAl[m][t][3]);
                accH[m][n] = __builtin_amdgcn_mfma_f32_16x16x32_bf16(Hh, BhH, accH[m][n], 0, 0, 0);
                accH[m][n] = __builtin_amdgcn_mfma_f32_16x16x32_bf16(Hh, BlH, accH[m][n], 0, 0, 0);
                accH[m][n] = __builtin_amdgcn_mfma_f32_16x16x32_bf16(Hl, BhH, accH[m][n], 0, 0, 0);
            }
        }
    }

#pragma unroll
    for (int m = 0; m < 2; m++)
#pragma unroll
        for (int ri = 0; ri < 4; ri++) {
            int row = base + 16 * m + 4 * g + ri;
            if (row < N_NODES) {
                float dv = (float)deg[row];
#pragma unroll
                for (int n = 0; n < 4; n++) {
                    int f = 16 * n + c16;
                    float r = sigm(accS[m][n][ri] + bb[f] + dv * bb[256 + f]);
                    float z = sigm(accS[m][4 + n][ri] + bb[64 + f] + dv * bb[256 + 64 + f]);
                    float ninn = accI[m][n][ri] + bb[128 + f] + dv * bb[384 + f];
                    float nh = accH[m][n][ri] + bb[192 + f];
                    float nn = tanh_fast(ninn + r * nh);
                    float hv = h[(size_t)row * 64 + f];
                    h[(size_t)row * 64 + f] = fmaxf((1.0f - z) * nn + z * hv, 0.0f);
                }
            }
        }
}

// ---------------- launch ----------------

extern "C" void kernel_launch(void* const* d_in, const int* in_sizes, int n_in,
                              void* d_out, int out_size, void* d_ws, size_t ws_size,
                              hipStream_t stream) {
    const int* x = (const int*)d_in[0];
    const int* ei = (const int*)d_in[1];
    const int* ea = (const int*)d_in[2];
    const int* batch = (const int*)d_in[3];
    const float* neW = (const float*)d_in[4];
    const float* neB = (const float*)d_in[5];
    const float* eeW = (const float*)d_in[6];
    const float* eeB = (const float*)d_in[7];
    const float* m0W = (const float*)d_in[8];
    const float* m0b = (const float*)d_in[9];
    const float* m1W = (const float*)d_in[10];
    const float* m1b = (const float*)d_in[11];
    const float* gWih = (const float*)d_in[12];
    const float* gbih = (const float*)d_in[13];
    const float* gWhh = (const float*)d_in[14];
    const float* gbhh = (const float*)d_in[15];
    const float* r0W = (const float*)d_in[16];
    const float* r0b = (const float*)d_in[17];
    const float* r1W = (const float*)d_in[18];
    const float* r1b = (const float*)d_in[19];

    float* ws = (float*)d_ws;

    const size_t OFF_H = 0;
    const size_t OFF_PA = 3200000;      // Pa; also temp eids during CSR build
    const size_t OFF_PB = 6400000;
    const size_t OFF_AGGMID = 9600000;
    const size_t OFF_SSORT = 12800000;  // packed (idx<<16|src)
    const size_t OFF_EAPK = 13600000;   // unused (kept for layout stability)
    const size_t OFF_DEG = 14400000;
    const size_t OFF_ROWPTR = 14460000;
    const size_t OFF_CURSOR = 14520000;
    const size_t OFF_CHUNK = 14580000;
    const size_t OFF_WF2 = 14590000;
    const size_t OFF_C = 14630000;
    const size_t OFF_B0P = 14631000;
    const size_t OFF_POOL = 14640000;   // pool (after layers); wf3+bb+Ptmp+LUT during setup/layers
    const size_t OFF_GPTR = 14780000;   // N_GRAPHS+1 ints
    const size_t FAST_F32 = 14790000;

    bool fast = ws_size >= FAST_F32 * sizeof(float);

    if (fast) {
        float* h = ws + OFF_H;
        float* Pa = ws + OFF_PA;
        float* Pb = ws + OFF_PB;
        float* aggmid = ws + OFF_AGGMID;
        int* eids = (int*)(ws + OFF_PA);   // temp during CSR build (before Pa live)
        unsigned int* spk = (unsigned int*)(ws + OFF_SSORT);
        int* deg = (int*)(ws + OFF_DEG);
        int* rowptr = (int*)(ws + OFF_ROWPTR);
        int* cursor = (int*)(ws + OFF_CURSOR);
        int* chunksum = (int*)(ws + OFF_CHUNK);
        unsigned int* wf2 = (unsigned int*)(ws + OFF_WF2);
        float* Cbuf = ws + OFF_C;
        float* b0p = ws + OFF_B0P;
        float* pool = ws + OFF_POOL;
        unsigned int* wf3 = (unsigned int*)(ws + OFF_POOL);       // 73728 u32
        float* bb = ws + OFF_POOL + 73728;                        // 1536 f32
        float* Ptmp = ws + OFF_POOL + 73728 + 1536;               // 3*PN f32
        float* lut = ws + OFF_POOL + 73728 + 1536 + 3 * PN;       // 3*LUTN f32
        int* gptr = (int*)(ws + OFF_GPTR);

        node_enc_kernel<<<(N_NODES * ND + 255) / 256, 256, 0, stream>>>(x, neW, neB, h);
        wsetup2_kernel<<<3, 256, 0, stream>>>(m0W, m0b, m1W, eeW, eeB, wf2, Cbuf, b0p);
        lut_kernel<<<(3 * LUTN + 255) / 256, 256, 0, stream>>>(Cbuf, lut);
        pmat_kernel<<<dim3(PMAT_BLOCKS, 3), 256, 0, stream>>>(gWih, m1W, m1b, Ptmp);
        wsetup3_kernel<<<3, 256, 0, stream>>>(gbih, gWhh, gbhh, Ptmp, wf3, bb);
        gptr_kernel<<<(N_NODES + 255) / 256, 256, 0, stream>>>(batch, gptr);

        hipMemsetAsync(deg, 0, N_NODES * sizeof(int), stream);
        hist_kernel<<<(N_EDGES + 255) / 256, 256, 0, stream>>>(ei, deg);
        scan1_kernel<<<NCHUNK, 256, 0, stream>>>(deg, rowptr, chunksum);
        scan2_kernel<<<1, 256, 0, stream>>>(chunksum);
        scan3_kernel<<<NCHUNK, 256, 0, stream>>>(rowptr, chunksum, cursor);
        scatter_kernel<<<(N_EDGES + 255) / 256, 256, 0, stream>>>(ei, cursor, eids);
        sortseg_kernel<<<(N_NODES + 3) / 4, 256, 0, stream>>>(rowptr, eids, ei, ea, spk);

        for (int l = 0; l < NL; l++) {
            ph_kernel<<<(PH_TILES + 3) / 4, 256, 0, stream>>>(
                h, wf2 + (size_t)l * WF2_STRIDE, b0p + l * 64, Pa, Pb);
            agg_edge_kernel<<<AGG_BLOCKS, 256, 0, stream>>>(
                Pa, Pb, spk, rowptr, lut + (size_t)l * LUTN, aggmid);
            gru_mfma2_kernel<<<(PH_TILES + 3) / 4, 256, 0, stream>>>(
                h, aggmid, deg, wf3 + (size_t)l * GRU_STRIDE, bb + (size_t)l * 512);
        }

        pool_seg_kernel<<<N_GRAPHS / 4, 256, 0, stream>>>(h, gptr, pool);
        readout2_kernel<<<N_GRAPHS / 4, 256, 0, stream>>>(pool, gptr, r0W, r0b, r1W, r1b,
                                                          (float*)d_out);
    } else {
        // round-4 fallback (fits in 26.2 MB)
        float* h = ws;
        float* agg = ws + 3200000;
        float* pool = ws + 6400000;
        float* cnt = ws + 6400000 + 131072;
        unsigned int* wfBase = (unsigned int*)(ws + 6400000);
        float* b0pBase = ws + 6400000 + 43008;

        node_enc_kernel<<<(N_NODES * ND + 255) / 256, 256, 0, stream>>>(x, neW, neB, h);
        wfrag_setup_kernel<<<3, 256, 0, stream>>>(m0W, m0b, m1W, eeW, eeB, wfBase, b0pBase);

        for (int l = 0; l < NL; l++) {
            hipMemsetAsync(agg, 0, (size_t)N_NODES * ND * sizeof(float), stream);
            msg_mfma_kernel<<<MSG_BLOCKS, 256, 0, stream>>>(
                h, ei, ea, wfBase + (size_t)l * WF_STRIDE, b0pBase + l * 64,
                m1b + (size_t)l * 64, agg);
            gru_kernel<<<(N_NODES + 15) / 16, 256, 0, stream>>>(
                h, agg,
                gWih + (size_t)l * 64 * 192, gbih + (size_t)l * 192,
                gWhh + (size_t)l * 64 * 192, gbhh + (size_t)l * 192);
        }

        hipMemsetAsync(pool, 0, (size_t)(N_GRAPHS * ND + N_GRAPHS) * sizeof(float), stream);
        pool_kernel<<<(N_NODES * ND + 255) / 256, 256, 0, stream>>>(h, batch, pool, cnt);
        readout_kernel<<<N_GRAPHS / 4, 256, 0, stream>>>(pool, cnt, r0W, r0b, r1W, r1b,
                                                         (float*)d_out);
    }
}